// Round 4
// baseline (389.657 us; speedup 1.0000x reference)
//
#include <hip/hip_runtime.h>
#include <hip/hip_bf16.h>
#include <math.h>

#define N_EMBD 768
#define N_HEAD 12
#define HEAD_DIM 64
#define TOKENS 8192   // B*T
#define SEQ 2048
#define BATCH 4
#define NQT (SEQ / 64)   // 32 query tiles per (b,h)

typedef __attribute__((ext_vector_type(8))) short short8;   // 8 bf16 = 4 VGPRs
typedef __attribute__((ext_vector_type(4))) short short4v;  // 4 bf16 = 8 B
typedef __attribute__((ext_vector_type(4))) float f32x4;

__device__ __forceinline__ short f2bf(float f) {
    unsigned u = __builtin_bit_cast(unsigned, f);
    unsigned r = (u + 0x7fffu + ((u >> 16) & 1u)) >> 16;   // RNE
    return (short)r;
}
__device__ __forceinline__ short f2bf_fast(float f) {      // round-half-up
    unsigned u = __builtin_bit_cast(unsigned, f);
    return (short)((u + 0x8000u) >> 16);
}

// fast GELU: x * sigmoid(1.5957691x(1+0.044715x^2)); |err| < ~4e-4
__device__ __forceinline__ float gelu_fast(float x) {
    float z = 1.5957691216057308f * x * (1.0f + 0.044715f * x * x);
    return x / (1.0f + __expf(-z));
}

// async global->LDS, 16B per lane; lds dest = wave-uniform base + lane*16
__device__ __forceinline__ void gld16(const void* g, void* l) {
    __builtin_amdgcn_global_load_lds(
        (const __attribute__((address_space(1))) unsigned int*)g,
        (__attribute__((address_space(3))) unsigned int*)l, 16, 0, 0);
}

// ---------- merged weight transpose: 4 matrices, one launch -----------------
// W[K][N] f32 -> Wt[N][K] bf16, 32x32 tiles, flat tile id over all 4.
__global__ __launch_bounds__(256) void wT_all(
        const float* __restrict__ Wa, short* __restrict__ Ta,    // 768x2304
        const float* __restrict__ Wp, short* __restrict__ Tp,    // 768x768
        const float* __restrict__ Wf, short* __restrict__ Tf,    // 768x3072
        const float* __restrict__ Wm, short* __restrict__ Tm) {  // 3072x768
    __shared__ float T[32][33];
    int id = blockIdx.x;
    const float* W; short* Wt; int K, N;
    if (id < 1728)      { W = Wa; Wt = Ta; K = 768;  N = 2304; }
    else if (id < 2304) { W = Wp; Wt = Tp; K = 768;  N = 768;  id -= 1728; }
    else if (id < 4608) { W = Wf; Wt = Tf; K = 768;  N = 3072; id -= 2304; }
    else                { W = Wm; Wt = Tm; K = 3072; N = 768;  id -= 4608; }
    int tn = N >> 5;
    int n0 = (id % tn) * 32, k0 = (id / tn) * 32;
    int c = threadIdx.x & 31, r0 = threadIdx.x >> 5;
#pragma unroll
    for (int i = 0; i < 32; i += 8)
        T[r0 + i][c] = W[(size_t)(k0 + r0 + i) * N + n0 + c];
    __syncthreads();
#pragma unroll
    for (int i = 0; i < 32; i += 8)
        Wt[(size_t)(n0 + r0 + i) * K + k0 + c] = f2bf(T[c][r0 + i]);
}

// ---------- LayerNorm fp32 in -> bf16 out, one WAVE per row (no barriers) ---
__global__ __launch_bounds__(256) void ln_bf_kernel(const float* __restrict__ x,
                                                    const float* __restrict__ w,
                                                    const float* __restrict__ b,
                                                    short* __restrict__ out) {
    int row = blockIdx.x * 4 + (threadIdx.x >> 6);
    int lane = threadIdx.x & 63;
    const float4* xr = (const float4*)(x + (size_t)row * N_EMBD);
    const float4* wr = (const float4*)w;
    const float4* br = (const float4*)b;

    float4 v[3];
#pragma unroll
    for (int i = 0; i < 3; ++i) v[i] = xr[lane + 64 * i];
    float s = 0.f;
#pragma unroll
    for (int i = 0; i < 3; ++i) s += v[i].x + v[i].y + v[i].z + v[i].w;
#pragma unroll
    for (int off = 1; off < 64; off <<= 1) s += __shfl_xor(s, off, 64);
    float mean = s * (1.f / 768.f);

    float var = 0.f;
#pragma unroll
    for (int i = 0; i < 3; ++i) {
        float a0 = v[i].x - mean, a1 = v[i].y - mean,
              a2 = v[i].z - mean, a3 = v[i].w - mean;
        var += a0 * a0 + a1 * a1 + a2 * a2 + a3 * a3;
    }
#pragma unroll
    for (int off = 1; off < 64; off <<= 1) var += __shfl_xor(var, off, 64);
    float inv = 1.f / (sqrtf(var * (1.f / 768.f)) + 1e-6f);

    short4v* yr = (short4v*)(out + (size_t)row * N_EMBD);
#pragma unroll
    for (int i = 0; i < 3; ++i) {
        float4 wv = wr[lane + 64 * i], bv = br[lane + 64 * i];
        short4v o;
        o[0] = f2bf(wv.x * (v[i].x - mean) * inv + bv.x);
        o[1] = f2bf(wv.y * (v[i].y - mean) * inv + bv.y);
        o[2] = f2bf(wv.z * (v[i].z - mean) * inv + bv.z);
        o[3] = f2bf(wv.w * (v[i].w - mean) * inv + bv.w);
        yr[lane + 64 * i] = o;
    }
}

// ---------- bf16 MFMA GEMM, 128x128 tile, counted-vmcnt 2-barrier K-loop ----
// K-loop sync (T4): raw s_barrier + counted s_waitcnt vmcnt(4), prefetch TWO
// tiles ahead (4 gld16/wave/tile, 8 in flight steady-state). gld16 has no
// register result, so the ONLY vmcnt waits are the explicit counted ones --
// no per-iteration vmcnt(0) drain (the __syncthreads structural stall).
// B1 releases buf[t] (each wave's own slice covered by its own vmcnt before
// the barrier); B2 guarantees all waves consumed buf[t] before stage(t+2)
// overwrites it.
// SWAP=1: operands swapped (mfma(b,a)): acc reg r walks consecutive N-cols ->
// 8B short4v stores, f32x4 bias. SWAP=0 keeps r on M-rows (VOUT V-transpose).
// VOUT: for V n-tiles (n0>=1536) of the qkv GEMM, write transposed into
// Vt[bh][d][t] as packed short4 (4 consecutive t) and skip the normal write.
template <int ACT, int VOUT, int SWAP>
__global__ __launch_bounds__(256) void gemm_mfma(
        const short* __restrict__ A,     // [M][K] bf16
        const short* __restrict__ Bt,    // [N][K] bf16
        const float* __restrict__ bias,
        short* __restrict__ outp,        // [M][N] bf16
        short* __restrict__ vt,          // [48][64][SEQ] (VOUT only)
        int M, int N, int K) {
    __shared__ short As[8192];   // 2 x (128 rows x 32 k)
    __shared__ short Bs[8192];
    int tid = threadIdx.x;
    int wave = tid >> 6, lane = tid & 63;
    int quad = lane >> 4, l15 = lane & 15;
    int m0 = blockIdx.x * 128, n0 = blockIdx.y * 128;
    int wm = wave >> 1, wn = wave & 1;
    int sr = lane >> 2, sc = (lane & 3) * 8;

    f32x4 acc[4][4];
#pragma unroll
    for (int i = 0; i < 4; ++i)
#pragma unroll
        for (int j = 0; j < 4; ++j) acc[i][j] = (f32x4){0.f, 0.f, 0.f, 0.f};

    const short* ag = A + (size_t)(m0 + wave * 32 + sr) * K + sc;
    const short* bg = Bt + (size_t)(n0 + wave * 32 + sr) * K + sc;
    int woff = wave * 1024;
    int nk = K >> 5;

    auto stage = [&](int t) {
        int nb = (t & 1) * 4096 + woff;
        int kn = t << 5;
        gld16(ag + kn, &As[nb]);
        gld16(ag + kn + (size_t)16 * K, &As[nb + 512]);
        gld16(bg + kn, &Bs[nb]);
        gld16(bg + kn + (size_t)16 * K, &Bs[nb + 512]);
    };

    stage(0);
    if (nk > 1) stage(1);

    for (int it = 0; it < nk; ++it) {
        if (it + 1 < nk) asm volatile("s_waitcnt vmcnt(4)" ::: "memory");
        else             asm volatile("s_waitcnt vmcnt(0)" ::: "memory");
        __builtin_amdgcn_s_barrier();
        __builtin_amdgcn_sched_barrier(0);   // pin ds_reads below B1
        int cb = (it & 1) * 4096;
        short8 af[4], bfr[4];
#pragma unroll
        for (int mt = 0; mt < 4; ++mt)
            af[mt] = *(const short8*)&As[cb + (wm * 64 + mt * 16 + l15) * 32 + quad * 8];
#pragma unroll
        for (int nt = 0; nt < 4; ++nt)
            bfr[nt] = *(const short8*)&Bs[cb + (wn * 64 + nt * 16 + l15) * 32 + quad * 8];
        asm volatile("s_waitcnt lgkmcnt(0)" ::: "memory");
        __builtin_amdgcn_sched_barrier(0);   // rule 18: MFMA stays below wait
        __builtin_amdgcn_s_setprio(1);
#pragma unroll
        for (int mt = 0; mt < 4; ++mt)
#pragma unroll
            for (int nt = 0; nt < 4; ++nt) {
                if (SWAP)
                    acc[mt][nt] = __builtin_amdgcn_mfma_f32_16x16x32_bf16(
                        bfr[nt], af[mt], acc[mt][nt], 0, 0, 0);
                else
                    acc[mt][nt] = __builtin_amdgcn_mfma_f32_16x16x32_bf16(
                        af[mt], bfr[nt], acc[mt][nt], 0, 0, 0);
            }
        __builtin_amdgcn_s_setprio(0);
        __builtin_amdgcn_sched_barrier(0);   // keep B2 after MFMA/reads
        __builtin_amdgcn_s_barrier();
        if (it + 2 < nk) stage(it + 2);      // overwrite buf[it&1], now free
    }

    if (SWAP) {
        // r walks N-cols: row = ...+l15 (per-lane), col = ...+quad*4+r
#pragma unroll
        for (int nt = 0; nt < 4; ++nt) {
            int colb = n0 + wn * 64 + nt * 16 + quad * 4;
            f32x4 b4 = *(const f32x4*)&bias[colb];
#pragma unroll
            for (int mt = 0; mt < 4; ++mt) {
                int row = m0 + wm * 64 + mt * 16 + l15;
                short4v o4;
#pragma unroll
                for (int r = 0; r < 4; ++r) {
                    float v = acc[mt][nt][r] + b4[r];
                    if (ACT) v = gelu_fast(v);
                    o4[r] = f2bf(v);
                }
                *(short4v*)&outp[(size_t)row * N + colb] = o4;
            }
        }
        return;
    }

    if (VOUT && n0 >= 1536) {
        // V tile: write transposed Vt[bh*64+d][t], 4 consecutive t per store
#pragma unroll
        for (int mt = 0; mt < 4; ++mt) {
            int row0 = m0 + wm * 64 + mt * 16 + quad * 4;
            int b = row0 >> 11, t0 = row0 & 2047;
#pragma unroll
            for (int nt = 0; nt < 4; ++nt) {
                int col = n0 + wn * 64 + nt * 16 + l15;
                int vcol = col - 1536;
                int bh = b * N_HEAD + (vcol >> 6);
                int d = vcol & 63;
                float bi = bias[col];
                short4v o;
#pragma unroll
                for (int r = 0; r < 4; ++r) o[r] = f2bf(acc[mt][nt][r] + bi);
                *(short4v*)&vt[((size_t)bh * 64 + d) * SEQ + t0] = o;
            }
        }
        return;
    }

#pragma unroll
    for (int mt = 0; mt < 4; ++mt) {
        int row0 = m0 + wm * 64 + mt * 16 + quad * 4;
#pragma unroll
        for (int nt = 0; nt < 4; ++nt) {
            int col = n0 + wn * 64 + nt * 16 + l15;
            float bi = bias[col];
#pragma unroll
            for (int r = 0; r < 4; ++r) {
                float v = acc[mt][nt][r] + bi;
                if (ACT) v = gelu_fast(v);
                outp[(size_t)(row0 + r) * N + col] = f2bf(v);
            }
        }
    }
}

// ---------- bf16 MFMA GEMM, 128x64 tile, counted-vmcnt 2-barrier K-loop -----
// Same sync scheme as gemm_mfma; 3 gld16/wave/tile -> steady wait vmcnt(3).
// Swapped operands: fp32 float4 res/out epilogue.
__global__ __launch_bounds__(256) void gemm_mfma_n64(
        const short* __restrict__ A,
        const short* __restrict__ Bt,
        const float* __restrict__ bias,
        const float* __restrict__ res,
        float* __restrict__ outp,
        int M, int N, int K) {
    __shared__ short As[8192];   // 2 x (128 x 32)
    __shared__ short Bs[4096];   // 2 x (64 x 32)
    int tid = threadIdx.x;
    int wave = tid >> 6, lane = tid & 63;
    int quad = lane >> 4, l15 = lane & 15;
    int m0 = blockIdx.x * 128, n0 = blockIdx.y * 64;
    int wm = wave >> 1, wn = wave & 1;
    int sr = lane >> 2, sc = (lane & 3) * 8;

    f32x4 acc[4][2];
#pragma unroll
    for (int i = 0; i < 4; ++i)
#pragma unroll
        for (int j = 0; j < 2; ++j) acc[i][j] = (f32x4){0.f, 0.f, 0.f, 0.f};

    const short* gptr[3];
    int loff[3];
    bool isa[3];
#pragma unroll
    for (int j = 0; j < 3; ++j) {
        int c = wave * 3 + j;
        if (c < 8) {
            gptr[j] = A + (size_t)(m0 + c * 16 + sr) * K + sc;
            loff[j] = c * 512; isa[j] = true;
        } else {
            gptr[j] = Bt + (size_t)(n0 + (c - 8) * 16 + sr) * K + sc;
            loff[j] = (c - 8) * 512; isa[j] = false;
        }
    }
    int nk = K >> 5;

    auto stage = [&](int t) {
        int nba = (t & 1) * 4096, nbb = (t & 1) * 2048;
        int kn = t << 5;
#pragma unroll
        for (int j = 0; j < 3; ++j)
            gld16(gptr[j] + kn, isa[j] ? &As[nba + loff[j]] : &Bs[nbb + loff[j]]);
    };

    stage(0);
    if (nk > 1) stage(1);

    for (int it = 0; it < nk; ++it) {
        if (it + 1 < nk) asm volatile("s_waitcnt vmcnt(3)" ::: "memory");
        else             asm volatile("s_waitcnt vmcnt(0)" ::: "memory");
        __builtin_amdgcn_s_barrier();
        __builtin_amdgcn_sched_barrier(0);
        int cba = (it & 1) * 4096, cbb = (it & 1) * 2048;
        short8 af[4], bfr[2];
#pragma unroll
        for (int mt = 0; mt < 4; ++mt)
            af[mt] = *(const short8*)&As[cba + (wm * 64 + mt * 16 + l15) * 32 + quad * 8];
#pragma unroll
        for (int nt = 0; nt < 2; ++nt)
            bfr[nt] = *(const short8*)&Bs[cbb + (wn * 32 + nt * 16 + l15) * 32 + quad * 8];
        asm volatile("s_waitcnt lgkmcnt(0)" ::: "memory");
        __builtin_amdgcn_sched_barrier(0);
        __builtin_amdgcn_s_setprio(1);
#pragma unroll
        for (int mt = 0; mt < 4; ++mt)
#pragma unroll
            for (int nt = 0; nt < 2; ++nt)
                acc[mt][nt] = __builtin_amdgcn_mfma_f32_16x16x32_bf16(
                    bfr[nt], af[mt], acc[mt][nt], 0, 0, 0);
        __builtin_amdgcn_s_setprio(0);
        __builtin_amdgcn_sched_barrier(0);
        __builtin_amdgcn_s_barrier();
        if (it + 2 < nk) stage(it + 2);
    }

    // swapped: row = ...+l15, col = ...+quad*4+r -> float4 res/out
#pragma unroll
    for (int nt = 0; nt < 2; ++nt) {
        int colb = n0 + wn * 32 + nt * 16 + quad * 4;
        f32x4 b4 = *(const f32x4*)&bias[colb];
#pragma unroll
        for (int mt = 0; mt < 4; ++mt) {
            int row = m0 + wm * 64 + mt * 16 + l15;
            f32x4 rv = *(const f32x4*)&res[(size_t)row * N + colb];
            f32x4 ov;
#pragma unroll
            for (int r = 0; r < 4; ++r) ov[r] = acc[mt][nt][r] + b4[r] + rv[r];
            *(f32x4*)&outp[(size_t)row * N + colb] = ov;
        }
    }
}

// ---------- bf16 MFMA flash attention (round-2 form) ------------------------
// Fixed-max softmax: p = exp2(s*0.125*log2e - 4*log2e); constant cancels in
// p/l. Row-sum l via MFMA with all-ones B fragment. K/V double-buffered in
// LDS (40 KB total -> 4 blocks/CU); Q lives in registers (16B/lane global
// loads from the L2-resident qkv). Diagonal kt peeled: main loop is
// mask-free. P-store swizzle: idx ^= quad<<4 (write) / ((l15>>2)&3)<<4
// (read) -- spreads each P ds_write across all 32 banks (2 lanes/bank =
// free), vs 8-way conflict unswizzled.
template <bool DIAG>
__device__ __forceinline__ void attn_kt(
        const short* __restrict__ Ks, const short* __restrict__ Vs,
        short* __restrict__ Ps, int cb,
        const short8* qf, short8 ones,
        f32x4* o, f32x4& lacc,
        int wave, int quad, int l15, int pswz) {
    f32x4 sacc[4];
#pragma unroll
    for (int nt = 0; nt < 4; ++nt) sacc[nt] = (f32x4){0.f, 0.f, 0.f, 0.f};
#pragma unroll
    for (int nt = 0; nt < 4; ++nt)
#pragma unroll
        for (int ks = 0; ks < 2; ++ks) {
            short8 kf = *(const short8*)&Ks[cb + ks * 2048 + (nt * 16 + l15) * 32 + quad * 8];
            sacc[nt] = __builtin_amdgcn_mfma_f32_16x16x32_bf16(qf[ks], kf, sacc[nt], 0, 0, 0);
        }

#pragma unroll
    for (int nt = 0; nt < 4; ++nt) {
        int scol = nt * 16 + l15;
        int base = (scol >> 5) * 2048 + (scol & 31);
#pragma unroll
        for (int r = 0; r < 4; ++r) {
            // exp(s*0.125 - 4) = exp2(s*0.18033688 - 5.77078), one fma + exp2
            float p = exp2f(fmaf(sacc[nt][r], 0.18033688011112042f,
                                 -5.770780163555854f));
            if (DIAG && (scol > wave * 16 + quad * 4 + r)) p = 0.f;
            Ps[(base + (wave * 16 + quad * 4 + r) * 32) ^ (quad << 4)] = f2bf_fast(p);
        }
    }

    short8 pf0 = *(const short8*)&Ps[((wave * 16 + l15) * 32 + quad * 8) ^ pswz];
    short8 pf1 = *(const short8*)&Ps[(2048 + (wave * 16 + l15) * 32 + quad * 8) ^ pswz];
    lacc = __builtin_amdgcn_mfma_f32_16x16x32_bf16(pf0, ones, lacc, 0, 0, 0);
    lacc = __builtin_amdgcn_mfma_f32_16x16x32_bf16(pf1, ones, lacc, 0, 0, 0);
#pragma unroll
    for (int nt = 0; nt < 4; ++nt) {
        short8 vf0 = *(const short8*)&Vs[cb + (nt * 16 + l15) * 32 + quad * 8];
        short8 vf1 = *(const short8*)&Vs[cb + 2048 + (nt * 16 + l15) * 32 + quad * 8];
        o[nt] = __builtin_amdgcn_mfma_f32_16x16x32_bf16(pf0, vf0, o[nt], 0, 0, 0);
        o[nt] = __builtin_amdgcn_mfma_f32_16x16x32_bf16(pf1, vf1, o[nt], 0, 0, 0);
    }
}

__device__ __forceinline__ void attn_tile(
        const short* __restrict__ qkv, const short* __restrict__ Vt,
        short* __restrict__ y, int bh, int qt,
        short* Ks, short* Vs, short* Ps) {
    int tid = threadIdx.x;
    int wave = tid >> 6, lane = tid & 63;
    int quad = lane >> 4, l15 = lane & 15;
    int h = bh % N_HEAD, b = bh / N_HEAD;
    size_t bT = (size_t)b * SEQ;
    int q0 = qt * 64;
    int sr = lane >> 2, sc = (lane & 3) * 8;

    const short ONE_BF = (short)0x3F80;
    short8 ones;
#pragma unroll
    for (int j = 0; j < 8; ++j) ones[j] = ONE_BF;

    // Q fragments straight from global (qkv is L2-resident per (b,h))
    const short* qrow = qkv + (bT + q0 + wave * 16 + l15) * 2304 + h * 64 + quad * 8;
    short8 qf[2];
    qf[0] = *(const short8*)qrow;
    qf[1] = *(const short8*)(qrow + 32);

    __syncthreads();               // LDS free (prior q-tile fully done)
    // stage K/V tile 0 (buf 0), one drain for all
#pragma unroll
    for (int j = 0; j < 4; ++j) {
        int c = wave * 4 + j;
        if (c < 8) {
            int sub = c >> 2, r0 = (c & 3) * 16;
            const short* g = qkv + (bT + r0 + sr) * 2304 + 768 + h * 64 + sub * 32 + sc;
            gld16(g, &Ks[sub * 2048 + r0 * 32]);
        } else {
            int cv = c - 8;
            int sub = cv >> 2, r0 = (cv & 3) * 16;
            const short* g = Vt + ((size_t)bh * 64 + r0 + sr) * SEQ + sub * 32 + sc;
            gld16(g, &Vs[sub * 2048 + r0 * 32]);
        }
    }
    __syncthreads();

    f32x4 o[4];
#pragma unroll
    for (int nt = 0; nt < 4; ++nt) o[nt] = (f32x4){0.f, 0.f, 0.f, 0.f};
    f32x4 lacc = (f32x4){0.f, 0.f, 0.f, 0.f};

    const int pswz = ((l15 >> 2) & 3) << 4;   // read-side P swizzle key

    // main loop: kt < qt, mask-free; always prefetches kt+1 (<= qt)
    for (int kt = 0; kt < qt; ++kt) {
        int cb = (kt & 1) * 4096;
        if (kt) __syncthreads();       // buf[kt&1] ready; other buf free
        int nb = ((kt + 1) & 1) * 4096;
        int k0n = (kt + 1) * 64;
#pragma unroll
        for (int j = 0; j < 4; ++j) {
            int c = wave * 4 + j;
            if (c < 8) {
                int sub = c >> 2, r0 = (c & 3) * 16;
                const short* g = qkv + (bT + k0n + r0 + sr) * 2304 + 768 + h * 64 + sub * 32 + sc;
                gld16(g, &Ks[nb + sub * 2048 + r0 * 32]);
            } else {
                int cv = c - 8;
                int sub = cv >> 2, r0 = (cv & 3) * 16;
                const short* g = Vt + ((size_t)bh * 64 + r0 + sr) * SEQ + k0n + sub * 32 + sc;
                gld16(g, &Vs[nb + sub * 2048 + r0 * 32]);
            }
        }
        attn_kt<false>(Ks, Vs, Ps, cb, qf, ones, o, lacc, wave, quad, l15, pswz);
    }

    // diagonal tile (kt == qt), masked
    if (qt) __syncthreads();
    attn_kt<true>(Ks, Vs, Ps, (qt & 1) * 4096, qf, ones, o, lacc,
                  wave, quad, l15, pswz);

    float inv[4];
#pragma unroll
    for (int r = 0; r < 4; ++r) inv[r] = 1.f / lacc[r];
#pragma unroll
    for (int nt = 0; nt < 4; ++nt)
#pragma unroll
        for (int r = 0; r < 4; ++r)
            y[(bT + q0 + wave * 16 + quad * 4 + r) * N_EMBD + h * 64 + nt * 16 + l15] =
                f2bf(o[nt][r] * inv[r]);
}

// Balanced pairing + XCD pinning (blockIdx.x = bh; 48%8==0 -> 6 heads/XCD).
// LDS 40 KB -> 4 blocks/CU (16 waves); launch_bounds(256,4) caps regs at 128.
__global__ __launch_bounds__(256, 4) void attn_mfma(
        const short* __restrict__ qkv, const short* __restrict__ Vt,
        short* __restrict__ y) {
    __shared__ short Ks[8192], Vs[8192], Ps[4096];   // 40 KB
    int bh = blockIdx.x;
    int pair = blockIdx.y;
    attn_tile(qkv, Vt, y, bh, pair, Ks, Vs, Ps);
    attn_tile(qkv, Vt, y, bh, NQT - 1 - pair, Ks, Vs, Ps);
}

extern "C" void kernel_launch(void* const* d_in, const int* in_sizes, int n_in,
                              void* d_out, int out_size, void* d_ws, size_t ws_size,
                              hipStream_t stream) {
    const float* x         = (const float*)d_in[0];
    const float* ln1_w     = (const float*)d_in[1];
    const float* ln1_b     = (const float*)d_in[2];
    const float* W_attn    = (const float*)d_in[3];
    const float* b_attn    = (const float*)d_in[4];
    const float* W_attn_pr = (const float*)d_in[5];
    const float* b_attn_pr = (const float*)d_in[6];
    const float* ln2_w     = (const float*)d_in[7];
    const float* ln2_b     = (const float*)d_in[8];
    const float* W_fc      = (const float*)d_in[9];
    const float* b_fc      = (const float*)d_in[10];
    const float* W_mlp_pr  = (const float*)d_in[11];
    const float* b_mlp_pr  = (const float*)d_in[12];
    float* out = (float*)d_out;

    const int M = TOKENS, C = N_EMBD;
    char* ws = (char*)d_ws;
    size_t region0 = (size_t)M * 3072 * 2;                  // qkv (37.7MB) | fc (50.3MB)
    short* qkv_bf = (short*)ws;
    short* fc_bf  = (short*)ws;
    size_t off = region0;
    short* VtB   = (short*)(ws + off); off += (size_t)48 * 64 * SEQ * 2;
    short* yb    = (short*)(ws + off); off += (size_t)M * C * 2;
    short* lnb   = (short*)(ws + off); off += (size_t)M * C * 2;
    float* x1    = (float*)(ws + off); off += (size_t)M * C * 4;
    short* WaT   = (short*)(ws + off); off += (size_t)2304 * 768 * 2;
    short* WpT   = (short*)(ws + off); off += (size_t)768 * 768 * 2;
    short* WfT   = (short*)(ws + off); off += (size_t)3072 * 768 * 2;
    short* WmT   = (short*)(ws + off); off += (size_t)768 * 3072 * 2;

    // 0. all weight transposes, one launch (fp32 [K][N] -> bf16 [N][K])
    wT_all<<<6912, 256, 0, stream>>>(W_attn, WaT, W_attn_pr, WpT,
                                     W_fc, WfT, W_mlp_pr, WmT);

    // 1. ln1 -> bf16 (wave per row)
    ln_bf_kernel<<<M / 4, 256, 0, stream>>>(x, ln1_w, ln1_b, lnb);

    // 2. qkv = ln1 @ W_attn + b -> bf16 [M][2304]; V tiles go straight to VtB
    gemm_mfma<0, 1, 0><<<dim3(M / 128, 2304 / 128), 256, 0, stream>>>(
        lnb, WaT, b_attn, qkv_bf, VtB, M, 2304, 768);

    // 3. attention -> yb bf16 (balanced pairing, bh-pinned XCDs, dbuf K/V)
    attn_mfma<<<dim3(BATCH * N_HEAD, NQT / 2), 256, 0, stream>>>(qkv_bf, VtB, yb);

    // 4. x1 = x + yb @ W_proj + b   (fp32 out), counted-vmcnt n64
    gemm_mfma_n64<<<dim3(M / 128, 768 / 64), 256, 0, stream>>>(
        yb, WpT, b_attn_pr, x, x1, M, 768, 768);

    // 5. ln2 -> bf16
    ln_bf_kernel<<<M / 4, 256, 0, stream>>>(x1, ln2_w, ln2_b, lnb);

    // 6. fc = gelu(ln2 @ W_fc + b) -> bf16 [M][3072]  (counted-vmcnt)
    gemm_mfma<1, 0, 1><<<dim3(M / 128, 3072 / 128), 256, 0, stream>>>(
        lnb, WfT, b_fc, fc_bf, nullptr, M, 3072, 768);

    // 7. out = x1 + fc @ W_mlp + b  (fp32 out), counted-vmcnt n64
    gemm_mfma_n64<<<dim3(M / 128, 768 / 64), 256, 0, stream>>>(
        fc_bf, WmT, b_mlp_pr, x1, out, M, 768, 3072);
}

// Round 5
// 376.874 us; speedup vs baseline: 1.0339x; 1.0339x over previous
//
#include <hip/hip_runtime.h>
#include <hip/hip_bf16.h>
#include <math.h>

#define N_EMBD 768
#define N_HEAD 12
#define HEAD_DIM 64
#define TOKENS 8192   // B*T
#define SEQ 2048
#define BATCH 4
#define NQT (SEQ / 64)   // 32 query tiles per (b,h)

typedef __attribute__((ext_vector_type(8))) short short8;   // 8 bf16 = 4 VGPRs
typedef __attribute__((ext_vector_type(4))) short short4v;  // 4 bf16 = 8 B
typedef __attribute__((ext_vector_type(4))) float f32x4;

__device__ __forceinline__ short f2bf(float f) {
    unsigned u = __builtin_bit_cast(unsigned, f);
    unsigned r = (u + 0x7fffu + ((u >> 16) & 1u)) >> 16;   // RNE
    return (short)r;
}
__device__ __forceinline__ short f2bf_fast(float f) {      // round-half-up
    unsigned u = __builtin_bit_cast(unsigned, f);
    return (short)((u + 0x8000u) >> 16);
}

// fast GELU: x * sigmoid(1.5957691x(1+0.044715x^2)); |err| < ~4e-4
__device__ __forceinline__ float gelu_fast(float x) {
    float z = 1.5957691216057308f * x * (1.0f + 0.044715f * x * x);
    return x / (1.0f + __expf(-z));
}

// async global->LDS, 16B per lane; lds dest = wave-uniform base + lane*16
__device__ __forceinline__ void gld16(const void* g, void* l) {
    __builtin_amdgcn_global_load_lds(
        (const __attribute__((address_space(1))) unsigned int*)g,
        (__attribute__((address_space(3))) unsigned int*)l, 16, 0, 0);
}

// ---------- merged weight transpose: 4 matrices, one launch -----------------
// W[K][N] f32 -> Wt[N][K] bf16, 32x32 tiles, flat tile id over all 4.
__global__ __launch_bounds__(256) void wT_all(
        const float* __restrict__ Wa, short* __restrict__ Ta,    // 768x2304
        const float* __restrict__ Wp, short* __restrict__ Tp,    // 768x768
        const float* __restrict__ Wf, short* __restrict__ Tf,    // 768x3072
        const float* __restrict__ Wm, short* __restrict__ Tm) {  // 3072x768
    __shared__ float T[32][33];
    int id = blockIdx.x;
    const float* W; short* Wt; int K, N;
    if (id < 1728)      { W = Wa; Wt = Ta; K = 768;  N = 2304; }
    else if (id < 2304) { W = Wp; Wt = Tp; K = 768;  N = 768;  id -= 1728; }
    else if (id < 4608) { W = Wf; Wt = Tf; K = 768;  N = 3072; id -= 2304; }
    else                { W = Wm; Wt = Tm; K = 3072; N = 768;  id -= 4608; }
    int tn = N >> 5;
    int n0 = (id % tn) * 32, k0 = (id / tn) * 32;
    int c = threadIdx.x & 31, r0 = threadIdx.x >> 5;
#pragma unroll
    for (int i = 0; i < 32; i += 8)
        T[r0 + i][c] = W[(size_t)(k0 + r0 + i) * N + n0 + c];
    __syncthreads();
#pragma unroll
    for (int i = 0; i < 32; i += 8)
        Wt[(size_t)(n0 + r0 + i) * K + k0 + c] = f2bf(T[c][r0 + i]);
}

// ---------- LayerNorm fp32 in -> bf16 out, one WAVE per row (no barriers) ---
__global__ __launch_bounds__(256) void ln_bf_kernel(const float* __restrict__ x,
                                                    const float* __restrict__ w,
                                                    const float* __restrict__ b,
                                                    short* __restrict__ out) {
    int row = blockIdx.x * 4 + (threadIdx.x >> 6);
    int lane = threadIdx.x & 63;
    const float4* xr = (const float4*)(x + (size_t)row * N_EMBD);
    const float4* wr = (const float4*)w;
    const float4* br = (const float4*)b;

    float4 v[3];
#pragma unroll
    for (int i = 0; i < 3; ++i) v[i] = xr[lane + 64 * i];
    float s = 0.f;
#pragma unroll
    for (int i = 0; i < 3; ++i) s += v[i].x + v[i].y + v[i].z + v[i].w;
#pragma unroll
    for (int off = 1; off < 64; off <<= 1) s += __shfl_xor(s, off, 64);
    float mean = s * (1.f / 768.f);

    float var = 0.f;
#pragma unroll
    for (int i = 0; i < 3; ++i) {
        float a0 = v[i].x - mean, a1 = v[i].y - mean,
              a2 = v[i].z - mean, a3 = v[i].w - mean;
        var += a0 * a0 + a1 * a1 + a2 * a2 + a3 * a3;
    }
#pragma unroll
    for (int off = 1; off < 64; off <<= 1) var += __shfl_xor(var, off, 64);
    float inv = 1.f / (sqrtf(var * (1.f / 768.f)) + 1e-6f);

    short4v* yr = (short4v*)(out + (size_t)row * N_EMBD);
#pragma unroll
    for (int i = 0; i < 3; ++i) {
        float4 wv = wr[lane + 64 * i], bv = br[lane + 64 * i];
        short4v o;
        o[0] = f2bf(wv.x * (v[i].x - mean) * inv + bv.x);
        o[1] = f2bf(wv.y * (v[i].y - mean) * inv + bv.y);
        o[2] = f2bf(wv.z * (v[i].z - mean) * inv + bv.z);
        o[3] = f2bf(wv.w * (v[i].w - mean) * inv + bv.w);
        yr[lane + 64 * i] = o;
    }
}

// ---------- bf16 MFMA GEMM, 128x128 tile, single-barrier dbuf K-loop --------
// (round-0 proven structure: one __syncthreads per K-step, compiler keeps its
// own fine-grained lgkmcnt interleave; counted-vmcnt variants measured WORSE
// -- m141-style regression.)
// SWAP=1: operands swapped (mfma(b,a)): acc reg r walks consecutive N-cols ->
// 8B short4v stores, f32x4 bias. SWAP=0 keeps r on M-rows (VOUT V-transpose).
// VOUT: for V n-tiles (n0>=1536) of the qkv GEMM, write transposed into
// Vt[bh][d][t] as packed short4 (4 consecutive t) and skip the normal write.
template <int ACT, int VOUT, int SWAP>
__global__ __launch_bounds__(256) void gemm_mfma(
        const short* __restrict__ A,     // [M][K] bf16
        const short* __restrict__ Bt,    // [N][K] bf16
        const float* __restrict__ bias,
        short* __restrict__ outp,        // [M][N] bf16
        short* __restrict__ vt,          // [48][64][SEQ] (VOUT only)
        int M, int N, int K) {
    __shared__ short As[8192];   // 2 x (128 rows x 32 k)
    __shared__ short Bs[8192];
    int tid = threadIdx.x;
    int wave = tid >> 6, lane = tid & 63;
    int quad = lane >> 4, l15 = lane & 15;
    int m0 = blockIdx.x * 128, n0 = blockIdx.y * 128;
    int wm = wave >> 1, wn = wave & 1;
    int sr = lane >> 2, sc = (lane & 3) * 8;

    f32x4 acc[4][4];
#pragma unroll
    for (int i = 0; i < 4; ++i)
#pragma unroll
        for (int j = 0; j < 4; ++j) acc[i][j] = (f32x4){0.f, 0.f, 0.f, 0.f};

    const short* ag = A + (size_t)(m0 + wave * 32 + sr) * K + sc;
    const short* bg = Bt + (size_t)(n0 + wave * 32 + sr) * K + sc;
    int woff = wave * 1024;

    gld16(ag, &As[woff]);
    gld16(ag + (size_t)16 * K, &As[woff + 512]);
    gld16(bg, &Bs[woff]);
    gld16(bg + (size_t)16 * K, &Bs[woff + 512]);

    int nk = K >> 5;
    for (int it = 0; it < nk; ++it) {
        int cb = (it & 1) * 4096;
        __syncthreads();               // buf[it&1] ready; other buf free
        if (it + 1 < nk) {
            int nb = ((it + 1) & 1) * 4096 + woff;
            int kn = (it + 1) << 5;
            gld16(ag + kn, &As[nb]);
            gld16(ag + kn + (size_t)16 * K, &As[nb + 512]);
            gld16(bg + kn, &Bs[nb]);
            gld16(bg + kn + (size_t)16 * K, &Bs[nb + 512]);
        }
        short8 af[4], bfr[4];
#pragma unroll
        for (int mt = 0; mt < 4; ++mt)
            af[mt] = *(const short8*)&As[cb + (wm * 64 + mt * 16 + l15) * 32 + quad * 8];
#pragma unroll
        for (int nt = 0; nt < 4; ++nt)
            bfr[nt] = *(const short8*)&Bs[cb + (wn * 64 + nt * 16 + l15) * 32 + quad * 8];
#pragma unroll
        for (int mt = 0; mt < 4; ++mt)
#pragma unroll
            for (int nt = 0; nt < 4; ++nt) {
                if (SWAP)
                    acc[mt][nt] = __builtin_amdgcn_mfma_f32_16x16x32_bf16(
                        bfr[nt], af[mt], acc[mt][nt], 0, 0, 0);
                else
                    acc[mt][nt] = __builtin_amdgcn_mfma_f32_16x16x32_bf16(
                        af[mt], bfr[nt], acc[mt][nt], 0, 0, 0);
            }
    }

    if (SWAP) {
        // r walks N-cols: row = ...+l15 (per-lane), col = ...+quad*4+r
#pragma unroll
        for (int nt = 0; nt < 4; ++nt) {
            int colb = n0 + wn * 64 + nt * 16 + quad * 4;
            f32x4 b4 = *(const f32x4*)&bias[colb];
#pragma unroll
            for (int mt = 0; mt < 4; ++mt) {
                int row = m0 + wm * 64 + mt * 16 + l15;
                short4v o4;
#pragma unroll
                for (int r = 0; r < 4; ++r) {
                    float v = acc[mt][nt][r] + b4[r];
                    if (ACT) v = gelu_fast(v);
                    o4[r] = f2bf(v);
                }
                *(short4v*)&outp[(size_t)row * N + colb] = o4;
            }
        }
        return;
    }

    if (VOUT && n0 >= 1536) {
        // V tile: write transposed Vt[bh*64+d][t], 4 consecutive t per store
#pragma unroll
        for (int mt = 0; mt < 4; ++mt) {
            int row0 = m0 + wm * 64 + mt * 16 + quad * 4;
            int b = row0 >> 11, t0 = row0 & 2047;
#pragma unroll
            for (int nt = 0; nt < 4; ++nt) {
                int col = n0 + wn * 64 + nt * 16 + l15;
                int vcol = col - 1536;
                int bh = b * N_HEAD + (vcol >> 6);
                int d = vcol & 63;
                float bi = bias[col];
                short4v o;
#pragma unroll
                for (int r = 0; r < 4; ++r) o[r] = f2bf(acc[mt][nt][r] + bi);
                *(short4v*)&vt[((size_t)bh * 64 + d) * SEQ + t0] = o;
            }
        }
        return;
    }

#pragma unroll
    for (int mt = 0; mt < 4; ++mt) {
        int row0 = m0 + wm * 64 + mt * 16 + quad * 4;
#pragma unroll
        for (int nt = 0; nt < 4; ++nt) {
            int col = n0 + wn * 64 + nt * 16 + l15;
            float bi = bias[col];
#pragma unroll
            for (int r = 0; r < 4; ++r) {
                float v = acc[mt][nt][r] + bi;
                if (ACT) v = gelu_fast(v);
                outp[(size_t)(row0 + r) * N + col] = f2bf(v);
            }
        }
    }
}

// ---------- bf16 MFMA GEMM, 128x64 tile, BK=64, single-barrier dbuf ---------
// BK=64: HALF the barrier+drain events of the BK=32 version (the n64 kernels
// are sync-dominated: MfmaUtil 19%, BW 15%), 16 MFMA per wave per barrier.
// LDS 48 KB (As 2x128x64, Bs 2x64x64). 24 gld16 chunks/tile = 6 per wave.
// Swapped operands: acc reg r walks N-cols -> float4 res/bias/out epilogue.
__global__ __launch_bounds__(256) void gemm_mfma_n64(
        const short* __restrict__ A,
        const short* __restrict__ Bt,
        const float* __restrict__ bias,
        const float* __restrict__ res,
        float* __restrict__ outp,
        int M, int N, int K) {
    __shared__ short As[16384];  // 2 x (128 rows x 64 k)
    __shared__ short Bs[8192];   // 2 x (64 rows x 64 k)
    int tid = threadIdx.x;
    int wave = tid >> 6, lane = tid & 63;
    int quad = lane >> 4, l15 = lane & 15;
    int m0 = blockIdx.x * 128, n0 = blockIdx.y * 64;
    int wm = wave >> 1, wn = wave & 1;
    int sr = lane >> 2, sc = (lane & 3) * 8;

    f32x4 acc[4][2];
#pragma unroll
    for (int i = 0; i < 4; ++i)
#pragma unroll
        for (int j = 0; j < 2; ++j) acc[i][j] = (f32x4){0.f, 0.f, 0.f, 0.f};

    // chunk c (0..23): c<16 -> A, ks=c>>3, rows (c&7)*16; else B, cb=c-16,
    // ks=cb>>2, rows (cb&3)*16. Each gld16 covers 16 rows x 32 k (1 KB).
    const short* gptr[6];
    int loff[6];
    bool isa[6];
#pragma unroll
    for (int j = 0; j < 6; ++j) {
        int c = wave * 6 + j;
        if (c < 16) {
            int ks = c >> 3, r0 = (c & 7) * 16;
            gptr[j] = A + (size_t)(m0 + r0 + sr) * K + ks * 32 + sc;
            loff[j] = ks * 4096 + r0 * 32; isa[j] = true;
        } else {
            int cb = c - 16;
            int ks = cb >> 2, r0 = (cb & 3) * 16;
            gptr[j] = Bt + (size_t)(n0 + r0 + sr) * K + ks * 32 + sc;
            loff[j] = ks * 2048 + r0 * 32; isa[j] = false;
        }
    }
    int nk = K >> 6;

    auto stage = [&](int t) {
        int ba = (t & 1) << 13, bb = (t & 1) << 12;
        int kn = t << 6;
#pragma unroll
        for (int j = 0; j < 6; ++j)
            gld16(gptr[j] + kn, isa[j] ? &As[ba + loff[j]] : &Bs[bb + loff[j]]);
    };

    stage(0);

    for (int it = 0; it < nk; ++it) {
        int cba = (it & 1) << 13, cbb = (it & 1) << 12;
        __syncthreads();               // buf[it&1] ready; other buf free
        if (it + 1 < nk) stage(it + 1);
#pragma unroll
        for (int ks = 0; ks < 2; ++ks) {
            short8 af[4], bfr[2];
#pragma unroll
            for (int mt = 0; mt < 4; ++mt)
                af[mt] = *(const short8*)&As[cba + ks * 4096 +
                                             (wm * 64 + mt * 16 + l15) * 32 + quad * 8];
#pragma unroll
            for (int nt = 0; nt < 2; ++nt)
                bfr[nt] = *(const short8*)&Bs[cbb + ks * 2048 +
                                              (wn * 32 + nt * 16 + l15) * 32 + quad * 8];
#pragma unroll
            for (int mt = 0; mt < 4; ++mt)
#pragma unroll
                for (int nt = 0; nt < 2; ++nt)
                    acc[mt][nt] = __builtin_amdgcn_mfma_f32_16x16x32_bf16(
                        bfr[nt], af[mt], acc[mt][nt], 0, 0, 0);
        }
    }

    // swapped: row = ...+l15, col = ...+quad*4+r -> float4 res/out
#pragma unroll
    for (int nt = 0; nt < 2; ++nt) {
        int colb = n0 + wn * 32 + nt * 16 + quad * 4;
        f32x4 b4 = *(const f32x4*)&bias[colb];
#pragma unroll
        for (int mt = 0; mt < 4; ++mt) {
            int row = m0 + wm * 64 + mt * 16 + l15;
            f32x4 rv = *(const f32x4*)&res[(size_t)row * N + colb];
            f32x4 ov;
#pragma unroll
            for (int r = 0; r < 4; ++r) ov[r] = acc[mt][nt][r] + b4[r] + rv[r];
            *(f32x4*)&outp[(size_t)row * N + colb] = ov;
        }
    }
}

// ---------- bf16 MFMA flash attention (round-2 form) ------------------------
// Fixed-max softmax: p = exp2(s*0.125*log2e - 4*log2e); constant cancels in
// p/l. Row-sum l via MFMA with all-ones B fragment. K/V double-buffered in
// LDS (40 KB total -> 4 blocks/CU); Q lives in registers (16B/lane global
// loads from the L2-resident qkv). Diagonal kt peeled: main loop is
// mask-free. P-store swizzle: idx ^= quad<<4 (write) / ((l15>>2)&3)<<4
// (read) -- spreads each P ds_write across all 32 banks (2 lanes/bank =
// free), vs 8-way conflict unswizzled.
template <bool DIAG>
__device__ __forceinline__ void attn_kt(
        const short* __restrict__ Ks, const short* __restrict__ Vs,
        short* __restrict__ Ps, int cb,
        const short8* qf, short8 ones,
        f32x4* o, f32x4& lacc,
        int wave, int quad, int l15, int pswz) {
    f32x4 sacc[4];
#pragma unroll
    for (int nt = 0; nt < 4; ++nt) sacc[nt] = (f32x4){0.f, 0.f, 0.f, 0.f};
#pragma unroll
    for (int nt = 0; nt < 4; ++nt)
#pragma unroll
        for (int ks = 0; ks < 2; ++ks) {
            short8 kf = *(const short8*)&Ks[cb + ks * 2048 + (nt * 16 + l15) * 32 + quad * 8];
            sacc[nt] = __builtin_amdgcn_mfma_f32_16x16x32_bf16(qf[ks], kf, sacc[nt], 0, 0, 0);
        }

#pragma unroll
    for (int nt = 0; nt < 4; ++nt) {
        int scol = nt * 16 + l15;
        int base = (scol >> 5) * 2048 + (scol & 31);
#pragma unroll
        for (int r = 0; r < 4; ++r) {
            // exp(s*0.125 - 4) = exp2(s*0.18033688 - 5.77078), one fma + exp2
            float p = exp2f(fmaf(sacc[nt][r], 0.18033688011112042f,
                                 -5.770780163555854f));
            if (DIAG && (scol > wave * 16 + quad * 4 + r)) p = 0.f;
            Ps[(base + (wave * 16 + quad * 4 + r) * 32) ^ (quad << 4)] = f2bf_fast(p);
        }
    }

    short8 pf0 = *(const short8*)&Ps[((wave * 16 + l15) * 32 + quad * 8) ^ pswz];
    short8 pf1 = *(const short8*)&Ps[(2048 + (wave * 16 + l15) * 32 + quad * 8) ^ pswz];
    lacc = __builtin_amdgcn_mfma_f32_16x16x32_bf16(pf0, ones, lacc, 0, 0, 0);
    lacc = __builtin_amdgcn_mfma_f32_16x16x32_bf16(pf1, ones, lacc, 0, 0, 0);
#pragma unroll
    for (int nt = 0; nt < 4; ++nt) {
        short8 vf0 = *(const short8*)&Vs[cb + (nt * 16 + l15) * 32 + quad * 8];
        short8 vf1 = *(const short8*)&Vs[cb + 2048 + (nt * 16 + l15) * 32 + quad * 8];
        o[nt] = __builtin_amdgcn_mfma_f32_16x16x32_bf16(pf0, vf0, o[nt], 0, 0, 0);
        o[nt] = __builtin_amdgcn_mfma_f32_16x16x32_bf16(pf1, vf1, o[nt], 0, 0, 0);
    }
}

__device__ __forceinline__ void attn_tile(
        const short* __restrict__ qkv, const short* __restrict__ Vt,
        short* __restrict__ y, int bh, int qt,
        short* Ks, short* Vs, short* Ps) {
    int tid = threadIdx.x;
    int wave = tid >> 6, lane = tid & 63;
    int quad = lane >> 4, l15 = lane & 15;
    int h = bh % N_HEAD, b = bh / N_HEAD;
    size_t bT = (size_t)b * SEQ;
    int q0 = qt * 64;
    int sr = lane >> 2, sc = (lane & 3) * 8;

    const short ONE_BF = (short)0x3F80;
    short8 ones;
#pragma unroll
    for (int j = 0; j < 8; ++j) ones[j] = ONE_BF;

    // Q fragments straight from global (qkv is L2-resident per (b,h))
    const short* qrow = qkv + (bT + q0 + wave * 16 + l15) * 2304 + h * 64 + quad * 8;
    short8 qf[2];
    qf[0] = *(const short8*)qrow;
    qf[1] = *(const short8*)(qrow + 32);

    __syncthreads();               // LDS free (prior q-tile fully done)
    // stage K/V tile 0 (buf 0), one drain for all
#pragma unroll
    for (int j = 0; j < 4; ++j) {
        int c = wave * 4 + j;
        if (c < 8) {
            int sub = c >> 2, r0 = (c & 3) * 16;
            const short* g = qkv + (bT + r0 + sr) * 2304 + 768 + h * 64 + sub * 32 + sc;
            gld16(g, &Ks[sub * 2048 + r0 * 32]);
        } else {
            int cv = c - 8;
            int sub = cv >> 2, r0 = (cv & 3) * 16;
            const short* g = Vt + ((size_t)bh * 64 + r0 + sr) * SEQ + sub * 32 + sc;
            gld16(g, &Vs[sub * 2048 + r0 * 32]);
        }
    }
    __syncthreads();

    f32x4 o[4];
#pragma unroll
    for (int nt = 0; nt < 4; ++nt) o[nt] = (f32x4){0.f, 0.f, 0.f, 0.f};
    f32x4 lacc = (f32x4){0.f, 0.f, 0.f, 0.f};

    const int pswz = ((l15 >> 2) & 3) << 4;   // read-side P swizzle key

    // main loop: kt < qt, mask-free; always prefetches kt+1 (<= qt)
    for (int kt = 0; kt < qt; ++kt) {
        int cb = (kt & 1) * 4096;
        if (kt) __syncthreads();       // buf[kt&1] ready; other buf free
        int nb = ((kt + 1) & 1) * 4096;
        int k0n = (kt + 1) * 64;
#pragma unroll
        for (int j = 0; j < 4; ++j) {
            int c = wave * 4 + j;
            if (c < 8) {
                int sub = c >> 2, r0 = (c & 3) * 16;
                const short* g = qkv + (bT + k0n + r0 + sr) * 2304 + 768 + h * 64 + sub * 32 + sc;
                gld16(g, &Ks[nb + sub * 2048 + r0 * 32]);
            } else {
                int cv = c - 8;
                int sub = cv >> 2, r0 = (cv & 3) * 16;
                const short* g = Vt + ((size_t)bh * 64 + r0 + sr) * SEQ + k0n + sub * 32 + sc;
                gld16(g, &Vs[nb + sub * 2048 + r0 * 32]);
            }
        }
        attn_kt<false>(Ks, Vs, Ps, cb, qf, ones, o, lacc, wave, quad, l15, pswz);
    }

    // diagonal tile (kt == qt), masked
    if (qt) __syncthreads();
    attn_kt<true>(Ks, Vs, Ps, (qt & 1) * 4096, qf, ones, o, lacc,
                  wave, quad, l15, pswz);

    float inv[4];
#pragma unroll
    for (int r = 0; r < 4; ++r) inv[r] = 1.f / lacc[r];
#pragma unroll
    for (int nt = 0; nt < 4; ++nt)
#pragma unroll
        for (int r = 0; r < 4; ++r)
            y[(bT + q0 + wave * 16 + quad * 4 + r) * N_EMBD + h * 64 + nt * 16 + l15] =
                f2bf(o[nt][r] * inv[r]);
}

// Balanced pairing + XCD pinning (blockIdx.x = bh; 48%8==0 -> 6 heads/XCD).
// LDS 40 KB -> 4 blocks/CU (16 waves); launch_bounds(256,4) caps regs at 128.
__global__ __launch_bounds__(256, 4) void attn_mfma(
        const short* __restrict__ qkv, const short* __restrict__ Vt,
        short* __restrict__ y) {
    __shared__ short Ks[8192], Vs[8192], Ps[4096];   // 40 KB
    int bh = blockIdx.x;
    int pair = blockIdx.y;
    attn_tile(qkv, Vt, y, bh, pair, Ks, Vs, Ps);
    attn_tile(qkv, Vt, y, bh, NQT - 1 - pair, Ks, Vs, Ps);
}

extern "C" void kernel_launch(void* const* d_in, const int* in_sizes, int n_in,
                              void* d_out, int out_size, void* d_ws, size_t ws_size,
                              hipStream_t stream) {
    const float* x         = (const float*)d_in[0];
    const float* ln1_w     = (const float*)d_in[1];
    const float* ln1_b     = (const float*)d_in[2];
    const float* W_attn    = (const float*)d_in[3];
    const float* b_attn    = (const float*)d_in[4];
    const float* W_attn_pr = (const float*)d_in[5];
    const float* b_attn_pr = (const float*)d_in[6];
    const float* ln2_w     = (const float*)d_in[7];
    const float* ln2_b     = (const float*)d_in[8];
    const float* W_fc      = (const float*)d_in[9];
    const float* b_fc      = (const float*)d_in[10];
    const float* W_mlp_pr  = (const float*)d_in[11];
    const float* b_mlp_pr  = (const float*)d_in[12];
    float* out = (float*)d_out;

    const int M = TOKENS, C = N_EMBD;
    char* ws = (char*)d_ws;
    size_t region0 = (size_t)M * 3072 * 2;                  // qkv (37.7MB) | fc (50.3MB)
    short* qkv_bf = (short*)ws;
    short* fc_bf  = (short*)ws;
    size_t off = region0;
    short* VtB   = (short*)(ws + off); off += (size_t)48 * 64 * SEQ * 2;
    short* yb    = (short*)(ws + off); off += (size_t)M * C * 2;
    short* lnb   = (short*)(ws + off); off += (size_t)M * C * 2;
    float* x1    = (float*)(ws + off); off += (size_t)M * C * 4;
    short* WaT   = (short*)(ws + off); off += (size_t)2304 * 768 * 2;
    short* WpT   = (short*)(ws + off); off += (size_t)768 * 768 * 2;
    short* WfT   = (short*)(ws + off); off += (size_t)3072 * 768 * 2;
    short* WmT   = (short*)(ws + off); off += (size_t)768 * 3072 * 2;

    // 0. all weight transposes, one launch (fp32 [K][N] -> bf16 [N][K])
    wT_all<<<6912, 256, 0, stream>>>(W_attn, WaT, W_attn_pr, WpT,
                                     W_fc, WfT, W_mlp_pr, WmT);

    // 1. ln1 -> bf16 (wave per row)
    ln_bf_kernel<<<M / 4, 256, 0, stream>>>(x, ln1_w, ln1_b, lnb);

    // 2. qkv = ln1 @ W_attn + b -> bf16 [M][2304]; V tiles go straight to VtB
    gemm_mfma<0, 1, 0><<<dim3(M / 128, 2304 / 128), 256, 0, stream>>>(
        lnb, WaT, b_attn, qkv_bf, VtB, M, 2304, 768);

    // 3. attention -> yb bf16 (balanced pairing, bh-pinned XCDs, dbuf K/V)
    attn_mfma<<<dim3(BATCH * N_HEAD, NQT / 2), 256, 0, stream>>>(qkv_bf, VtB, yb);

    // 4. x1 = x + yb @ W_proj + b   (fp32 out), BK=64 n64
    gemm_mfma_n64<<<dim3(M / 128, 768 / 64), 256, 0, stream>>>(
        yb, WpT, b_attn_pr, x, x1, M, 768, 768);

    // 5. ln2 -> bf16
    ln_bf_kernel<<<M / 4, 256, 0, stream>>>(x1, ln2_w, ln2_b, lnb);

    // 6. fc = gelu(ln2 @ W_fc + b) -> bf16 [M][3072]  (swapped epilogue)
    gemm_mfma<1, 0, 1><<<dim3(M / 128, 3072 / 128), 256, 0, stream>>>(
        lnb, WfT, b_fc, fc_bf, nullptr, M, 3072, 768);

    // 7. out = x1 + fc @ W_mlp + b  (fp32 out), BK=64 n64
    gemm_mfma_n64<<<dim3(M / 128, 768 / 64), 256, 0, stream>>>(
        fc_bf, WmT, b_mlp_pr, x1, out, M, 768, 3072);
}

// Round 6
// 371.464 us; speedup vs baseline: 1.0490x; 1.0146x over previous
//
#include <hip/hip_runtime.h>
#include <hip/hip_bf16.h>
#include <math.h>

#define N_EMBD 768
#define N_HEAD 12
#define HEAD_DIM 64
#define TOKENS 8192   // B*T
#define SEQ 2048
#define BATCH 4
#define NQT (SEQ / 64)   // 32 query tiles per (b,h)

typedef __attribute__((ext_vector_type(8))) short short8;   // 8 bf16 = 4 VGPRs
typedef __attribute__((ext_vector_type(4))) short short4v;  // 4 bf16 = 8 B
typedef __attribute__((ext_vector_type(4))) float f32x4;

__device__ __forceinline__ short f2bf(float f) {
    unsigned u = __builtin_bit_cast(unsigned, f);
    unsigned r = (u + 0x7fffu + ((u >> 16) & 1u)) >> 16;   // RNE
    return (short)r;
}
__device__ __forceinline__ short f2bf_fast(float f) {      // round-half-up
    unsigned u = __builtin_bit_cast(unsigned, f);
    return (short)((u + 0x8000u) >> 16);
}

// raw v_exp_f32 (exp2): exp2f() without fast-math lowers to a guarded
// multi-instruction sequence; the bare builtin is 1 trans instr.
__device__ __forceinline__ float exp2_raw(float x) {
#if __has_builtin(__builtin_amdgcn_exp2f)
    return __builtin_amdgcn_exp2f(x);
#else
    return exp2f(x);
#endif
}

// fast GELU: x * sigmoid(1.5957691x(1+0.044715x^2)); |err| < ~4e-4
__device__ __forceinline__ float gelu_fast(float x) {
    float z = 1.5957691216057308f * x * (1.0f + 0.044715f * x * x);
    return x / (1.0f + __expf(-z));
}

// async global->LDS, 16B per lane; lds dest = wave-uniform base + lane*16
__device__ __forceinline__ void gld16(const void* g, void* l) {
    __builtin_amdgcn_global_load_lds(
        (const __attribute__((address_space(1))) unsigned int*)g,
        (__attribute__((address_space(3))) unsigned int*)l, 16, 0, 0);
}

// ---------- merged weight transpose: 4 matrices, one launch -----------------
// W[K][N] f32 -> Wt[N][K] bf16, 32x32 tiles, flat tile id over all 4.
__global__ __launch_bounds__(256) void wT_all(
        const float* __restrict__ Wa, short* __restrict__ Ta,    // 768x2304
        const float* __restrict__ Wp, short* __restrict__ Tp,    // 768x768
        const float* __restrict__ Wf, short* __restrict__ Tf,    // 768x3072
        const float* __restrict__ Wm, short* __restrict__ Tm) {  // 3072x768
    __shared__ float T[32][33];
    int id = blockIdx.x;
    const float* W; short* Wt; int K, N;
    if (id < 1728)      { W = Wa; Wt = Ta; K = 768;  N = 2304; }
    else if (id < 2304) { W = Wp; Wt = Tp; K = 768;  N = 768;  id -= 1728; }
    else if (id < 4608) { W = Wf; Wt = Tf; K = 768;  N = 3072; id -= 2304; }
    else                { W = Wm; Wt = Tm; K = 3072; N = 768;  id -= 4608; }
    int tn = N >> 5;
    int n0 = (id % tn) * 32, k0 = (id / tn) * 32;
    int c = threadIdx.x & 31, r0 = threadIdx.x >> 5;
#pragma unroll
    for (int i = 0; i < 32; i += 8)
        T[r0 + i][c] = W[(size_t)(k0 + r0 + i) * N + n0 + c];
    __syncthreads();
#pragma unroll
    for (int i = 0; i < 32; i += 8)
        Wt[(size_t)(n0 + r0 + i) * K + k0 + c] = f2bf(T[c][r0 + i]);
}

// ---------- LayerNorm fp32 in -> bf16 out, one WAVE per row (no barriers) ---
__global__ __launch_bounds__(256) void ln_bf_kernel(const float* __restrict__ x,
                                                    const float* __restrict__ w,
                                                    const float* __restrict__ b,
                                                    short* __restrict__ out) {
    int row = blockIdx.x * 4 + (threadIdx.x >> 6);
    int lane = threadIdx.x & 63;
    const float4* xr = (const float4*)(x + (size_t)row * N_EMBD);
    const float4* wr = (const float4*)w;
    const float4* br = (const float4*)b;

    float4 v[3];
#pragma unroll
    for (int i = 0; i < 3; ++i) v[i] = xr[lane + 64 * i];
    float s = 0.f;
#pragma unroll
    for (int i = 0; i < 3; ++i) s += v[i].x + v[i].y + v[i].z + v[i].w;
#pragma unroll
    for (int off = 1; off < 64; off <<= 1) s += __shfl_xor(s, off, 64);
    float mean = s * (1.f / 768.f);

    float var = 0.f;
#pragma unroll
    for (int i = 0; i < 3; ++i) {
        float a0 = v[i].x - mean, a1 = v[i].y - mean,
              a2 = v[i].z - mean, a3 = v[i].w - mean;
        var += a0 * a0 + a1 * a1 + a2 * a2 + a3 * a3;
    }
#pragma unroll
    for (int off = 1; off < 64; off <<= 1) var += __shfl_xor(var, off, 64);
    float inv = 1.f / (sqrtf(var * (1.f / 768.f)) + 1e-6f);

    short4v* yr = (short4v*)(out + (size_t)row * N_EMBD);
#pragma unroll
    for (int i = 0; i < 3; ++i) {
        float4 wv = wr[lane + 64 * i], bv = br[lane + 64 * i];
        short4v o;
        o[0] = f2bf(wv.x * (v[i].x - mean) * inv + bv.x);
        o[1] = f2bf(wv.y * (v[i].y - mean) * inv + bv.y);
        o[2] = f2bf(wv.z * (v[i].z - mean) * inv + bv.z);
        o[3] = f2bf(wv.w * (v[i].w - mean) * inv + bv.w);
        yr[lane + 64 * i] = o;
    }
}

// ---------- bf16 MFMA GEMM, 128x128 tile, single-barrier dbuf K-loop --------
// (round-0 proven structure: one __syncthreads per K-step, compiler keeps its
// own fine-grained lgkmcnt interleave; counted-vmcnt variants measured WORSE
// -- m141-style regression.)
// SWAP=1: operands swapped (mfma(b,a)): acc reg r walks consecutive N-cols ->
// 8B short4v stores, f32x4 bias. SWAP=0 keeps r on M-rows (VOUT V-transpose).
// VOUT: for V n-tiles (n0>=1536) of the qkv GEMM, write transposed into
// Vt[bh][d][t] as packed short4 (4 consecutive t) and skip the normal write.
template <int ACT, int VOUT, int SWAP>
__global__ __launch_bounds__(256) void gemm_mfma(
        const short* __restrict__ A,     // [M][K] bf16
        const short* __restrict__ Bt,    // [N][K] bf16
        const float* __restrict__ bias,
        short* __restrict__ outp,        // [M][N] bf16
        short* __restrict__ vt,          // [48][64][SEQ] (VOUT only)
        int M, int N, int K) {
    __shared__ short As[8192];   // 2 x (128 rows x 32 k)
    __shared__ short Bs[8192];
    int tid = threadIdx.x;
    int wave = tid >> 6, lane = tid & 63;
    int quad = lane >> 4, l15 = lane & 15;
    int m0 = blockIdx.x * 128, n0 = blockIdx.y * 128;
    int wm = wave >> 1, wn = wave & 1;
    int sr = lane >> 2, sc = (lane & 3) * 8;

    f32x4 acc[4][4];
#pragma unroll
    for (int i = 0; i < 4; ++i)
#pragma unroll
        for (int j = 0; j < 4; ++j) acc[i][j] = (f32x4){0.f, 0.f, 0.f, 0.f};

    const short* ag = A + (size_t)(m0 + wave * 32 + sr) * K + sc;
    const short* bg = Bt + (size_t)(n0 + wave * 32 + sr) * K + sc;
    int woff = wave * 1024;

    gld16(ag, &As[woff]);
    gld16(ag + (size_t)16 * K, &As[woff + 512]);
    gld16(bg, &Bs[woff]);
    gld16(bg + (size_t)16 * K, &Bs[woff + 512]);

    int nk = K >> 5;
    for (int it = 0; it < nk; ++it) {
        int cb = (it & 1) * 4096;
        __syncthreads();               // buf[it&1] ready; other buf free
        if (it + 1 < nk) {
            int nb = ((it + 1) & 1) * 4096 + woff;
            int kn = (it + 1) << 5;
            gld16(ag + kn, &As[nb]);
            gld16(ag + kn + (size_t)16 * K, &As[nb + 512]);
            gld16(bg + kn, &Bs[nb]);
            gld16(bg + kn + (size_t)16 * K, &Bs[nb + 512]);
        }
        short8 af[4], bfr[4];
#pragma unroll
        for (int mt = 0; mt < 4; ++mt)
            af[mt] = *(const short8*)&As[cb + (wm * 64 + mt * 16 + l15) * 32 + quad * 8];
#pragma unroll
        for (int nt = 0; nt < 4; ++nt)
            bfr[nt] = *(const short8*)&Bs[cb + (wn * 64 + nt * 16 + l15) * 32 + quad * 8];
#pragma unroll
        for (int mt = 0; mt < 4; ++mt)
#pragma unroll
            for (int nt = 0; nt < 4; ++nt) {
                if (SWAP)
                    acc[mt][nt] = __builtin_amdgcn_mfma_f32_16x16x32_bf16(
                        bfr[nt], af[mt], acc[mt][nt], 0, 0, 0);
                else
                    acc[mt][nt] = __builtin_amdgcn_mfma_f32_16x16x32_bf16(
                        af[mt], bfr[nt], acc[mt][nt], 0, 0, 0);
            }
    }

    if (SWAP) {
        // r walks N-cols: row = ...+l15 (per-lane), col = ...+quad*4+r
#pragma unroll
        for (int nt = 0; nt < 4; ++nt) {
            int colb = n0 + wn * 64 + nt * 16 + quad * 4;
            f32x4 b4 = *(const f32x4*)&bias[colb];
#pragma unroll
            for (int mt = 0; mt < 4; ++mt) {
                int row = m0 + wm * 64 + mt * 16 + l15;
                short4v o4;
#pragma unroll
                for (int r = 0; r < 4; ++r) {
                    float v = acc[mt][nt][r] + b4[r];
                    if (ACT) v = gelu_fast(v);
                    o4[r] = f2bf(v);
                }
                *(short4v*)&outp[(size_t)row * N + colb] = o4;
            }
        }
        return;
    }

    if (VOUT && n0 >= 1536) {
        // V tile: write transposed Vt[bh*64+d][t], 4 consecutive t per store
#pragma unroll
        for (int mt = 0; mt < 4; ++mt) {
            int row0 = m0 + wm * 64 + mt * 16 + quad * 4;
            int b = row0 >> 11, t0 = row0 & 2047;
#pragma unroll
            for (int nt = 0; nt < 4; ++nt) {
                int col = n0 + wn * 64 + nt * 16 + l15;
                int vcol = col - 1536;
                int bh = b * N_HEAD + (vcol >> 6);
                int d = vcol & 63;
                float bi = bias[col];
                short4v o;
#pragma unroll
                for (int r = 0; r < 4; ++r) o[r] = f2bf(acc[mt][nt][r] + bi);
                *(short4v*)&vt[((size_t)bh * 64 + d) * SEQ + t0] = o;
            }
        }
        return;
    }

#pragma unroll
    for (int mt = 0; mt < 4; ++mt) {
        int row0 = m0 + wm * 64 + mt * 16 + quad * 4;
#pragma unroll
        for (int nt = 0; nt < 4; ++nt) {
            int col = n0 + wn * 64 + nt * 16 + l15;
            float bi = bias[col];
#pragma unroll
            for (int r = 0; r < 4; ++r) {
                float v = acc[mt][nt][r] + bi;
                if (ACT) v = gelu_fast(v);
                outp[(size_t)(row0 + r) * N + col] = f2bf(v);
            }
        }
    }
}

// ---------- bf16 MFMA GEMM, 128x64 tile, BK=64, single-barrier dbuf ---------
// BK=64: HALF the barrier+drain events of the BK=32 version (the n64 kernels
// are sync-dominated: MfmaUtil 19%, BW 15%), 16 MFMA per wave per barrier.
// LDS 48 KB (As 2x128x64, Bs 2x64x64). 24 gld16 chunks/tile = 6 per wave.
// Swapped operands: acc reg r walks N-cols -> float4 res/bias/out epilogue.
__global__ __launch_bounds__(256) void gemm_mfma_n64(
        const short* __restrict__ A,
        const short* __restrict__ Bt,
        const float* __restrict__ bias,
        const float* __restrict__ res,
        float* __restrict__ outp,
        int M, int N, int K) {
    __shared__ short As[16384];  // 2 x (128 rows x 64 k)
    __shared__ short Bs[8192];   // 2 x (64 rows x 64 k)
    int tid = threadIdx.x;
    int wave = tid >> 6, lane = tid & 63;
    int quad = lane >> 4, l15 = lane & 15;
    int m0 = blockIdx.x * 128, n0 = blockIdx.y * 64;
    int wm = wave >> 1, wn = wave & 1;
    int sr = lane >> 2, sc = (lane & 3) * 8;

    f32x4 acc[4][2];
#pragma unroll
    for (int i = 0; i < 4; ++i)
#pragma unroll
        for (int j = 0; j < 2; ++j) acc[i][j] = (f32x4){0.f, 0.f, 0.f, 0.f};

    // chunk c (0..23): c<16 -> A, ks=c>>3, rows (c&7)*16; else B, cb=c-16,
    // ks=cb>>2, rows (cb&3)*16. Each gld16 covers 16 rows x 32 k (1 KB).
    const short* gptr[6];
    int loff[6];
    bool isa[6];
#pragma unroll
    for (int j = 0; j < 6; ++j) {
        int c = wave * 6 + j;
        if (c < 16) {
            int ks = c >> 3, r0 = (c & 7) * 16;
            gptr[j] = A + (size_t)(m0 + r0 + sr) * K + ks * 32 + sc;
            loff[j] = ks * 4096 + r0 * 32; isa[j] = true;
        } else {
            int cb = c - 16;
            int ks = cb >> 2, r0 = (cb & 3) * 16;
            gptr[j] = Bt + (size_t)(n0 + r0 + sr) * K + ks * 32 + sc;
            loff[j] = ks * 2048 + r0 * 32; isa[j] = false;
        }
    }
    int nk = K >> 6;

    auto stage = [&](int t) {
        int ba = (t & 1) << 13, bb = (t & 1) << 12;
        int kn = t << 6;
#pragma unroll
        for (int j = 0; j < 6; ++j)
            gld16(gptr[j] + kn, isa[j] ? &As[ba + loff[j]] : &Bs[bb + loff[j]]);
    };

    stage(0);

    for (int it = 0; it < nk; ++it) {
        int cba = (it & 1) << 13, cbb = (it & 1) << 12;
        __syncthreads();               // buf[it&1] ready; other buf free
        if (it + 1 < nk) stage(it + 1);
#pragma unroll
        for (int ks = 0; ks < 2; ++ks) {
            short8 af[4], bfr[2];
#pragma unroll
            for (int mt = 0; mt < 4; ++mt)
                af[mt] = *(const short8*)&As[cba + ks * 4096 +
                                             (wm * 64 + mt * 16 + l15) * 32 + quad * 8];
#pragma unroll
            for (int nt = 0; nt < 2; ++nt)
                bfr[nt] = *(const short8*)&Bs[cbb + ks * 2048 +
                                              (wn * 32 + nt * 16 + l15) * 32 + quad * 8];
#pragma unroll
            for (int mt = 0; mt < 4; ++mt)
#pragma unroll
                for (int nt = 0; nt < 2; ++nt)
                    acc[mt][nt] = __builtin_amdgcn_mfma_f32_16x16x32_bf16(
                        bfr[nt], af[mt], acc[mt][nt], 0, 0, 0);
        }
    }

    // swapped: row = ...+l15, col = ...+quad*4+r -> float4 res/out
#pragma unroll
    for (int nt = 0; nt < 2; ++nt) {
        int colb = n0 + wn * 32 + nt * 16 + quad * 4;
        f32x4 b4 = *(const f32x4*)&bias[colb];
#pragma unroll
        for (int mt = 0; mt < 4; ++mt) {
            int row = m0 + wm * 64 + mt * 16 + l15;
            f32x4 rv = *(const f32x4*)&res[(size_t)row * N + colb];
            f32x4 ov;
#pragma unroll
            for (int r = 0; r < 4; ++r) ov[r] = acc[mt][nt][r] + b4[r] + rv[r];
            *(f32x4*)&outp[(size_t)row * N + colb] = ov;
        }
    }
}

// ---------- bf16 MFMA flash attention -------------------------------------
// Fixed-max softmax: p = exp2(s*0.125*log2e - 4*log2e) via RAW v_exp_f32
// (exp2f without fast-math lowers to a guarded ~6-8 instr sequence -- the
// measured 3.5x VALU inflation). Row-sum l via MFMA with all-ones B
// fragment. K/V double-buffered in LDS (40 KB -> 4 blocks/CU); Q in
// registers. Staging pointers hoisted out of the kt loop (constant-stride
// advance). Diagonal kt peeled. P-store swizzle: idx ^= quad<<4 (write) /
// ((l15>>2)&3)<<4 (read) -- all 32 banks, 2 lanes/bank = free.
template <bool DIAG>
__device__ __forceinline__ void attn_kt(
        const short* __restrict__ Ks, const short* __restrict__ Vs,
        short* __restrict__ Ps, int cb,
        const short8* qf, short8 ones,
        f32x4* o, f32x4& lacc,
        int wave, int quad, int l15, int pswz) {
    f32x4 sacc[4];
#pragma unroll
    for (int nt = 0; nt < 4; ++nt) sacc[nt] = (f32x4){0.f, 0.f, 0.f, 0.f};
#pragma unroll
    for (int nt = 0; nt < 4; ++nt)
#pragma unroll
        for (int ks = 0; ks < 2; ++ks) {
            short8 kf = *(const short8*)&Ks[cb + ks * 2048 + (nt * 16 + l15) * 32 + quad * 8];
            sacc[nt] = __builtin_amdgcn_mfma_f32_16x16x32_bf16(qf[ks], kf, sacc[nt], 0, 0, 0);
        }

#pragma unroll
    for (int nt = 0; nt < 4; ++nt) {
        int scol = nt * 16 + l15;
        int base = (scol >> 5) * 2048 + (scol & 31);
#pragma unroll
        for (int r = 0; r < 4; ++r) {
            // exp(s*0.125 - 4) = exp2(s*0.18033688 - 5.77078): 1 fma + 1 v_exp
            float p = exp2_raw(fmaf(sacc[nt][r], 0.18033688011112042f,
                                    -5.770780163555854f));
            if (DIAG && (scol > wave * 16 + quad * 4 + r)) p = 0.f;
            Ps[(base + (wave * 16 + quad * 4 + r) * 32) ^ (quad << 4)] = f2bf_fast(p);
        }
    }

    short8 pf0 = *(const short8*)&Ps[((wave * 16 + l15) * 32 + quad * 8) ^ pswz];
    short8 pf1 = *(const short8*)&Ps[(2048 + (wave * 16 + l15) * 32 + quad * 8) ^ pswz];
    lacc = __builtin_amdgcn_mfma_f32_16x16x32_bf16(pf0, ones, lacc, 0, 0, 0);
    lacc = __builtin_amdgcn_mfma_f32_16x16x32_bf16(pf1, ones, lacc, 0, 0, 0);
#pragma unroll
    for (int nt = 0; nt < 4; ++nt) {
        short8 vf0 = *(const short8*)&Vs[cb + (nt * 16 + l15) * 32 + quad * 8];
        short8 vf1 = *(const short8*)&Vs[cb + 2048 + (nt * 16 + l15) * 32 + quad * 8];
        o[nt] = __builtin_amdgcn_mfma_f32_16x16x32_bf16(pf0, vf0, o[nt], 0, 0, 0);
        o[nt] = __builtin_amdgcn_mfma_f32_16x16x32_bf16(pf1, vf1, o[nt], 0, 0, 0);
    }
}

__device__ __forceinline__ void attn_tile(
        const short* __restrict__ qkv, const short* __restrict__ Vt,
        short* __restrict__ y, int bh, int qt,
        short* Ks, short* Vs, short* Ps) {
    int tid = threadIdx.x;
    int wave = tid >> 6, lane = tid & 63;
    int quad = lane >> 4, l15 = lane & 15;
    int h = bh % N_HEAD, b = bh / N_HEAD;
    size_t bT = (size_t)b * SEQ;
    int q0 = qt * 64;
    int sr = lane >> 2, sc = (lane & 3) * 8;

    const short ONE_BF = (short)0x3F80;
    short8 ones;
#pragma unroll
    for (int j = 0; j < 8; ++j) ones[j] = ONE_BF;

    // Q fragments straight from global (qkv is L2-resident per (b,h))
    const short* qrow = qkv + (bT + q0 + wave * 16 + l15) * 2304 + h * 64 + quad * 8;
    short8 qf[2];
    qf[0] = *(const short8*)qrow;
    qf[1] = *(const short8*)(qrow + 32);

    // hoisted staging pointers: computed once, constant-stride advance per kt
    const short* gp[4];
    int lo[4], adv[4];
#pragma unroll
    for (int j = 0; j < 4; ++j) {
        int c = wave * 4 + j;
        if (c < 8) {
            int sub = c >> 2, r0 = (c & 3) * 16;
            gp[j] = qkv + (bT + r0 + sr) * 2304 + 768 + h * 64 + sub * 32 + sc;
            lo[j] = sub * 2048 + r0 * 32;
            adv[j] = 64 * 2304;          // next K-tile: +64 token rows
        } else {
            int cv = c - 8;
            int sub = cv >> 2, r0 = (cv & 3) * 16;
            gp[j] = Vt + ((size_t)bh * 64 + r0 + sr) * SEQ + sub * 32 + sc;
            lo[j] = sub * 2048 + r0 * 32;
            adv[j] = 64;                 // next K-tile: +64 t columns
        }
    }

    __syncthreads();               // LDS free (prior q-tile fully done)
    // stage K/V tile 0 (buf 0), one drain for all
#pragma unroll
    for (int j = 0; j < 4; ++j)
        gld16(gp[j], (wave * 4 + j < 8) ? &Ks[lo[j]] : &Vs[lo[j]]);
#pragma unroll
    for (int j = 0; j < 4; ++j) gp[j] += adv[j];   // now point at tile 1
    __syncthreads();

    f32x4 o[4];
#pragma unroll
    for (int nt = 0; nt < 4; ++nt) o[nt] = (f32x4){0.f, 0.f, 0.f, 0.f};
    f32x4 lacc = (f32x4){0.f, 0.f, 0.f, 0.f};

    const int pswz = ((l15 >> 2) & 3) << 4;   // read-side P swizzle key

    // main loop: kt < qt, mask-free; always prefetches kt+1 (<= qt)
    for (int kt = 0; kt < qt; ++kt) {
        int cb = (kt & 1) * 4096;
        if (kt) __syncthreads();       // buf[kt&1] ready; other buf free
        int nb = ((kt + 1) & 1) * 4096;
#pragma unroll
        for (int j = 0; j < 4; ++j) {
            gld16(gp[j], (wave * 4 + j < 8) ? &Ks[nb + lo[j]] : &Vs[nb + lo[j]]);
            gp[j] += adv[j];
        }
        attn_kt<false>(Ks, Vs, Ps, cb, qf, ones, o, lacc, wave, quad, l15, pswz);
    }

    // diagonal tile (kt == qt), masked
    if (qt) __syncthreads();
    attn_kt<true>(Ks, Vs, Ps, (qt & 1) * 4096, qf, ones, o, lacc,
                  wave, quad, l15, pswz);

    float inv[4];
#pragma unroll
    for (int r = 0; r < 4; ++r) inv[r] = 1.f / lacc[r];
#pragma unroll
    for (int nt = 0; nt < 4; ++nt)
#pragma unroll
        for (int r = 0; r < 4; ++r)
            y[(bT + q0 + wave * 16 + quad * 4 + r) * N_EMBD + h * 64 + nt * 16 + l15] =
                f2bf(o[nt][r] * inv[r]);
}

// Balanced pairing + XCD pinning (blockIdx.x = bh; 48%8==0 -> 6 heads/XCD).
// LDS 40 KB -> 4 blocks/CU (16 waves); launch_bounds(256,4) caps regs at 128.
__global__ __launch_bounds__(256, 4) void attn_mfma(
        const short* __restrict__ qkv, const short* __restrict__ Vt,
        short* __restrict__ y) {
    __shared__ short Ks[8192], Vs[8192], Ps[4096];   // 40 KB
    int bh = blockIdx.x;
    int pair = blockIdx.y;
    attn_tile(qkv, Vt, y, bh, pair, Ks, Vs, Ps);
    attn_tile(qkv, Vt, y, bh, NQT - 1 - pair, Ks, Vs, Ps);
}

extern "C" void kernel_launch(void* const* d_in, const int* in_sizes, int n_in,
                              void* d_out, int out_size, void* d_ws, size_t ws_size,
                              hipStream_t stream) {
    const float* x         = (const float*)d_in[0];
    const float* ln1_w     = (const float*)d_in[1];
    const float* ln1_b     = (const float*)d_in[2];
    const float* W_attn    = (const float*)d_in[3];
    const float* b_attn    = (const float*)d_in[4];
    const float* W_attn_pr = (const float*)d_in[5];
    const float* b_attn_pr = (const float*)d_in[6];
    const float* ln2_w     = (const float*)d_in[7];
    const float* ln2_b     = (const float*)d_in[8];
    const float* W_fc      = (const float*)d_in[9];
    const float* b_fc      = (const float*)d_in[10];
    const float* W_mlp_pr  = (const float*)d_in[11];
    const float* b_mlp_pr  = (const float*)d_in[12];
    float* out = (float*)d_out;

    const int M = TOKENS, C = N_EMBD;
    char* ws = (char*)d_ws;
    size_t region0 = (size_t)M * 3072 * 2;                  // qkv (37.7MB) | fc (50.3MB)
    short* qkv_bf = (short*)ws;
    short* fc_bf  = (short*)ws;
    size_t off = region0;
    short* VtB   = (short*)(ws + off); off += (size_t)48 * 64 * SEQ * 2;
    short* yb    = (short*)(ws + off); off += (size_t)M * C * 2;
    short* lnb   = (short*)(ws + off); off += (size_t)M * C * 2;
    float* x1    = (float*)(ws + off); off += (size_t)M * C * 4;
    short* WaT   = (short*)(ws + off); off += (size_t)2304 * 768 * 2;
    short* WpT   = (short*)(ws + off); off += (size_t)768 * 768 * 2;
    short* WfT   = (short*)(ws + off); off += (size_t)3072 * 768 * 2;
    short* WmT   = (short*)(ws + off); off += (size_t)768 * 3072 * 2;

    // 0. all weight transposes, one launch (fp32 [K][N] -> bf16 [N][K])
    wT_all<<<6912, 256, 0, stream>>>(W_attn, WaT, W_attn_pr, WpT,
                                     W_fc, WfT, W_mlp_pr, WmT);

    // 1. ln1 -> bf16 (wave per row)
    ln_bf_kernel<<<M / 4, 256, 0, stream>>>(x, ln1_w, ln1_b, lnb);

    // 2. qkv = ln1 @ W_attn + b -> bf16 [M][2304]; V tiles go straight to VtB
    gemm_mfma<0, 1, 0><<<dim3(M / 128, 2304 / 128), 256, 0, stream>>>(
        lnb, WaT, b_attn, qkv_bf, VtB, M, 2304, 768);

    // 3. attention -> yb bf16 (balanced pairing, bh-pinned XCDs, dbuf K/V)
    attn_mfma<<<dim3(BATCH * N_HEAD, NQT / 2), 256, 0, stream>>>(qkv_bf, VtB, yb);

    // 4. x1 = x + yb @ W_proj + b   (fp32 out), BK=64 n64
    gemm_mfma_n64<<<dim3(M / 128, 768 / 64), 256, 0, stream>>>(
        yb, WpT, b_attn_pr, x, x1, M, 768, 768);

    // 5. ln2 -> bf16
    ln_bf_kernel<<<M / 4, 256, 0, stream>>>(x1, ln2_w, ln2_b, lnb);

    // 6. fc = gelu(ln2 @ W_fc + b) -> bf16 [M][3072]  (swapped epilogue)
    gemm_mfma<1, 0, 1><<<dim3(M / 128, 3072 / 128), 256, 0, stream>>>(
        lnb, WfT, b_fc, fc_bf, nullptr, M, 3072, 768);

    // 7. out = x1 + fc @ W_mlp + b  (fp32 out), BK=64 n64
    gemm_mfma_n64<<<dim3(M / 128, 768 / 64), 256, 0, stream>>>(
        fc_bf, WmT, b_mlp_pr, x1, out, M, 768, 3072);
}

// Round 7
// 350.328 us; speedup vs baseline: 1.1123x; 1.0603x over previous
//
#include <hip/hip_runtime.h>
#include <hip/hip_bf16.h>
#include <math.h>

#define N_EMBD 768
#define N_HEAD 12
#define HEAD_DIM 64
#define TOKENS 8192   // B*T
#define SEQ 2048
#define BATCH 4
#define NQT (SEQ / 64)   // 32 query tiles per (b,h)

typedef __attribute__((ext_vector_type(8))) short short8;   // 8 bf16 = 4 VGPRs
typedef __attribute__((ext_vector_type(4))) short short4v;  // 4 bf16 = 8 B
typedef __attribute__((ext_vector_type(4))) float f32x4;

__device__ __forceinline__ short f2bf(float f) {
    unsigned u = __builtin_bit_cast(unsigned, f);
    unsigned r = (u + 0x7fffu + ((u >> 16) & 1u)) >> 16;   // RNE
    return (short)r;
}
__device__ __forceinline__ short f2bf_fast(float f) {      // round-half-up
    unsigned u = __builtin_bit_cast(unsigned, f);
    return (short)((u + 0x8000u) >> 16);
}

// raw v_exp_f32 (exp2): exp2f() without fast-math lowers to a guarded
// multi-instruction sequence; the bare builtin is 1 trans instr.
__device__ __forceinline__ float exp2_raw(float x) {
#if __has_builtin(__builtin_amdgcn_exp2f)
    return __builtin_amdgcn_exp2f(x);
#else
    return exp2f(x);
#endif
}

// fast GELU: x * sigmoid(1.5957691x(1+0.044715x^2)); |err| < ~4e-4
__device__ __forceinline__ float gelu_fast(float x) {
    float z = 1.5957691216057308f * x * (1.0f + 0.044715f * x * x);
    return x / (1.0f + __expf(-z));
}

// async global->LDS, 16B per lane; lds dest = wave-uniform base + lane*16
__device__ __forceinline__ void gld16(const void* g, void* l) {
    __builtin_amdgcn_global_load_lds(
        (const __attribute__((address_space(1))) unsigned int*)g,
        (__attribute__((address_space(3))) unsigned int*)l, 16, 0, 0);
}

// ---------- merged weight transpose: 4 matrices, one launch -----------------
// W[K][N] f32 -> Wt[N][K] bf16, 32x32 tiles, flat tile id over all 4.
__global__ __launch_bounds__(256) void wT_all(
        const float* __restrict__ Wa, short* __restrict__ Ta,    // 768x2304
        const float* __restrict__ Wp, short* __restrict__ Tp,    // 768x768
        const float* __restrict__ Wf, short* __restrict__ Tf,    // 768x3072
        const float* __restrict__ Wm, short* __restrict__ Tm) {  // 3072x768
    __shared__ float T[32][33];
    int id = blockIdx.x;
    const float* W; short* Wt; int K, N;
    if (id < 1728)      { W = Wa; Wt = Ta; K = 768;  N = 2304; }
    else if (id < 2304) { W = Wp; Wt = Tp; K = 768;  N = 768;  id -= 1728; }
    else if (id < 4608) { W = Wf; Wt = Tf; K = 768;  N = 3072; id -= 2304; }
    else                { W = Wm; Wt = Tm; K = 3072; N = 768;  id -= 4608; }
    int tn = N >> 5;
    int n0 = (id % tn) * 32, k0 = (id / tn) * 32;
    int c = threadIdx.x & 31, r0 = threadIdx.x >> 5;
#pragma unroll
    for (int i = 0; i < 32; i += 8)
        T[r0 + i][c] = W[(size_t)(k0 + r0 + i) * N + n0 + c];
    __syncthreads();
#pragma unroll
    for (int i = 0; i < 32; i += 8)
        Wt[(size_t)(n0 + r0 + i) * K + k0 + c] = f2bf(T[c][r0 + i]);
}

// ---------- LayerNorm fp32 in -> bf16 out, one WAVE per row (no barriers) ---
__global__ __launch_bounds__(256) void ln_bf_kernel(const float* __restrict__ x,
                                                    const float* __restrict__ w,
                                                    const float* __restrict__ b,
                                                    short* __restrict__ out) {
    int row = blockIdx.x * 4 + (threadIdx.x >> 6);
    int lane = threadIdx.x & 63;
    const float4* xr = (const float4*)(x + (size_t)row * N_EMBD);
    const float4* wr = (const float4*)w;
    const float4* br = (const float4*)b;

    float4 v[3];
#pragma unroll
    for (int i = 0; i < 3; ++i) v[i] = xr[lane + 64 * i];
    float s = 0.f;
#pragma unroll
    for (int i = 0; i < 3; ++i) s += v[i].x + v[i].y + v[i].z + v[i].w;
#pragma unroll
    for (int off = 1; off < 64; off <<= 1) s += __shfl_xor(s, off, 64);
    float mean = s * (1.f / 768.f);

    float var = 0.f;
#pragma unroll
    for (int i = 0; i < 3; ++i) {
        float a0 = v[i].x - mean, a1 = v[i].y - mean,
              a2 = v[i].z - mean, a3 = v[i].w - mean;
        var += a0 * a0 + a1 * a1 + a2 * a2 + a3 * a3;
    }
#pragma unroll
    for (int off = 1; off < 64; off <<= 1) var += __shfl_xor(var, off, 64);
    float inv = 1.f / (sqrtf(var * (1.f / 768.f)) + 1e-6f);

    short4v* yr = (short4v*)(out + (size_t)row * N_EMBD);
#pragma unroll
    for (int i = 0; i < 3; ++i) {
        float4 wv = wr[lane + 64 * i], bv = br[lane + 64 * i];
        short4v o;
        o[0] = f2bf(wv.x * (v[i].x - mean) * inv + bv.x);
        o[1] = f2bf(wv.y * (v[i].y - mean) * inv + bv.y);
        o[2] = f2bf(wv.z * (v[i].z - mean) * inv + bv.z);
        o[3] = f2bf(wv.w * (v[i].w - mean) * inv + bv.w);
        yr[lane + 64 * i] = o;
    }
}

// ---------- bf16 MFMA GEMM, 128x128 tile, BK=64, single-barrier dbuf --------
// BK=64: half the barrier+drain windows of BK=32 (24->12 at K=768), 32 MFMA
// per wave per window (the BK=64 lever already paid on the n64 kernels).
// LDS 64 KB (As/Bs each 2buf x 2ks x 128 x 32) -> 2 blocks/CU (measured
// effective occupancy was already ~2 blocks at BK=32).
// SWAP=1: operands swapped (mfma(b,a)): acc reg r walks consecutive N-cols ->
// 8B short4v stores, f32x4 bias. SWAP=0 keeps r on M-rows (VOUT V-transpose).
// VOUT: for V n-tiles (n0>=1536) of the qkv GEMM, write transposed into
// Vt[bh][d][t] as packed short4 (4 consecutive t) and skip the normal write.
template <int ACT, int VOUT, int SWAP>
__global__ __launch_bounds__(256) void gemm_mfma(
        const short* __restrict__ A,     // [M][K] bf16
        const short* __restrict__ Bt,    // [N][K] bf16
        const float* __restrict__ bias,
        short* __restrict__ outp,        // [M][N] bf16
        short* __restrict__ vt,          // [48][64][SEQ] (VOUT only)
        int M, int N, int K) {
    __shared__ short As[16384];  // 2 buf x (2 ks x 128 rows x 32 k)
    __shared__ short Bs[16384];
    int tid = threadIdx.x;
    int wave = tid >> 6, lane = tid & 63;
    int quad = lane >> 4, l15 = lane & 15;
    int m0 = blockIdx.x * 128, n0 = blockIdx.y * 128;
    int wm = wave >> 1, wn = wave & 1;
    int sr = lane >> 2, sc = (lane & 3) * 8;

    f32x4 acc[4][4];
#pragma unroll
    for (int i = 0; i < 4; ++i)
#pragma unroll
        for (int j = 0; j < 4; ++j) acc[i][j] = (f32x4){0.f, 0.f, 0.f, 0.f};

    // 32 chunks/tile (16 A + 16 B), 8 per wave; chunk = 16 rows x 32 k (1 KB)
    const short* gp[8];
    int lo[8];
    bool ia[8];
#pragma unroll
    for (int j = 0; j < 8; ++j) {
        int c = wave * 8 + j;
        if (c < 16) {
            int ks = c >> 3, r0 = (c & 7) * 16;
            gp[j] = A + (size_t)(m0 + r0 + sr) * K + ks * 32 + sc;
            lo[j] = ks * 4096 + r0 * 32; ia[j] = true;
        } else {
            int cc = c - 16, ks = cc >> 3, r0 = (cc & 7) * 16;
            gp[j] = Bt + (size_t)(n0 + r0 + sr) * K + ks * 32 + sc;
            lo[j] = ks * 4096 + r0 * 32; ia[j] = false;
        }
    }
    int nk = K >> 6;

    auto stage = [&](int t) {
        int bb = (t & 1) * 8192;
        int kn = t << 6;
#pragma unroll
        for (int j = 0; j < 8; ++j)
            gld16(gp[j] + kn, ia[j] ? &As[bb + lo[j]] : &Bs[bb + lo[j]]);
    };

    stage(0);

    for (int it = 0; it < nk; ++it) {
        int cb = (it & 1) * 8192;
        __syncthreads();               // buf[it&1] ready; other buf free
        if (it + 1 < nk) stage(it + 1);
#pragma unroll
        for (int ks = 0; ks < 2; ++ks) {
            short8 af[4], bfr[4];
#pragma unroll
            for (int mt = 0; mt < 4; ++mt)
                af[mt] = *(const short8*)&As[cb + ks * 4096 +
                                             (wm * 64 + mt * 16 + l15) * 32 + quad * 8];
#pragma unroll
            for (int nt = 0; nt < 4; ++nt)
                bfr[nt] = *(const short8*)&Bs[cb + ks * 4096 +
                                              (wn * 64 + nt * 16 + l15) * 32 + quad * 8];
#pragma unroll
            for (int mt = 0; mt < 4; ++mt)
#pragma unroll
                for (int nt = 0; nt < 4; ++nt) {
                    if (SWAP)
                        acc[mt][nt] = __builtin_amdgcn_mfma_f32_16x16x32_bf16(
                            bfr[nt], af[mt], acc[mt][nt], 0, 0, 0);
                    else
                        acc[mt][nt] = __builtin_amdgcn_mfma_f32_16x16x32_bf16(
                            af[mt], bfr[nt], acc[mt][nt], 0, 0, 0);
                }
        }
    }

    if (SWAP) {
        // r walks N-cols: row = ...+l15 (per-lane), col = ...+quad*4+r
#pragma unroll
        for (int nt = 0; nt < 4; ++nt) {
            int colb = n0 + wn * 64 + nt * 16 + quad * 4;
            f32x4 b4 = *(const f32x4*)&bias[colb];
#pragma unroll
            for (int mt = 0; mt < 4; ++mt) {
                int row = m0 + wm * 64 + mt * 16 + l15;
                short4v o4;
#pragma unroll
                for (int r = 0; r < 4; ++r) {
                    float v = acc[mt][nt][r] + b4[r];
                    if (ACT) v = gelu_fast(v);
                    o4[r] = f2bf(v);
                }
                *(short4v*)&outp[(size_t)row * N + colb] = o4;
            }
        }
        return;
    }

    if (VOUT && n0 >= 1536) {
        // V tile: write transposed Vt[bh*64+d][t], 4 consecutive t per store
#pragma unroll
        for (int mt = 0; mt < 4; ++mt) {
            int row0 = m0 + wm * 64 + mt * 16 + quad * 4;
            int b = row0 >> 11, t0 = row0 & 2047;
#pragma unroll
            for (int nt = 0; nt < 4; ++nt) {
                int col = n0 + wn * 64 + nt * 16 + l15;
                int vcol = col - 1536;
                int bh = b * N_HEAD + (vcol >> 6);
                int d = vcol & 63;
                float bi = bias[col];
                short4v o;
#pragma unroll
                for (int r = 0; r < 4; ++r) o[r] = f2bf(acc[mt][nt][r] + bi);
                *(short4v*)&vt[((size_t)bh * 64 + d) * SEQ + t0] = o;
            }
        }
        return;
    }

#pragma unroll
    for (int mt = 0; mt < 4; ++mt) {
        int row0 = m0 + wm * 64 + mt * 16 + quad * 4;
#pragma unroll
        for (int nt = 0; nt < 4; ++nt) {
            int col = n0 + wn * 64 + nt * 16 + l15;
            float bi = bias[col];
#pragma unroll
            for (int r = 0; r < 4; ++r) {
                float v = acc[mt][nt][r] + bi;
                if (ACT) v = gelu_fast(v);
                outp[(size_t)(row0 + r) * N + col] = f2bf(v);
            }
        }
    }
}

// ---------- bf16 MFMA GEMM, 128x64 tile, BK=64, single-barrier dbuf ---------
// Swapped operands: acc reg r walks N-cols -> float4 res/bias/out epilogue.
__global__ __launch_bounds__(256) void gemm_mfma_n64(
        const short* __restrict__ A,
        const short* __restrict__ Bt,
        const float* __restrict__ bias,
        const float* __restrict__ res,
        float* __restrict__ outp,
        int M, int N, int K) {
    __shared__ short As[16384];  // 2 x (128 rows x 64 k)
    __shared__ short Bs[8192];   // 2 x (64 rows x 64 k)
    int tid = threadIdx.x;
    int wave = tid >> 6, lane = tid & 63;
    int quad = lane >> 4, l15 = lane & 15;
    int m0 = blockIdx.x * 128, n0 = blockIdx.y * 64;
    int wm = wave >> 1, wn = wave & 1;
    int sr = lane >> 2, sc = (lane & 3) * 8;

    f32x4 acc[4][2];
#pragma unroll
    for (int i = 0; i < 4; ++i)
#pragma unroll
        for (int j = 0; j < 2; ++j) acc[i][j] = (f32x4){0.f, 0.f, 0.f, 0.f};

    // chunk c (0..23): c<16 -> A, ks=c>>3, rows (c&7)*16; else B, cb=c-16,
    // ks=cb>>2, rows (cb&3)*16. Each gld16 covers 16 rows x 32 k (1 KB).
    const short* gptr[6];
    int loff[6];
    bool isa[6];
#pragma unroll
    for (int j = 0; j < 6; ++j) {
        int c = wave * 6 + j;
        if (c < 16) {
            int ks = c >> 3, r0 = (c & 7) * 16;
            gptr[j] = A + (size_t)(m0 + r0 + sr) * K + ks * 32 + sc;
            loff[j] = ks * 4096 + r0 * 32; isa[j] = true;
        } else {
            int cb = c - 16;
            int ks = cb >> 2, r0 = (cb & 3) * 16;
            gptr[j] = Bt + (size_t)(n0 + r0 + sr) * K + ks * 32 + sc;
            loff[j] = ks * 2048 + r0 * 32; isa[j] = false;
        }
    }
    int nk = K >> 6;

    auto stage = [&](int t) {
        int ba = (t & 1) << 13, bb = (t & 1) << 12;
        int kn = t << 6;
#pragma unroll
        for (int j = 0; j < 6; ++j)
            gld16(gptr[j] + kn, isa[j] ? &As[ba + loff[j]] : &Bs[bb + loff[j]]);
    };

    stage(0);

    for (int it = 0; it < nk; ++it) {
        int cba = (it & 1) << 13, cbb = (it & 1) << 12;
        __syncthreads();               // buf[it&1] ready; other buf free
        if (it + 1 < nk) stage(it + 1);
#pragma unroll
        for (int ks = 0; ks < 2; ++ks) {
            short8 af[4], bfr[2];
#pragma unroll
            for (int mt = 0; mt < 4; ++mt)
                af[mt] = *(const short8*)&As[cba + ks * 4096 +
                                             (wm * 64 + mt * 16 + l15) * 32 + quad * 8];
#pragma unroll
            for (int nt = 0; nt < 2; ++nt)
                bfr[nt] = *(const short8*)&Bs[cbb + ks * 2048 +
                                              (wn * 32 + nt * 16 + l15) * 32 + quad * 8];
#pragma unroll
            for (int mt = 0; mt < 4; ++mt)
#pragma unroll
                for (int nt = 0; nt < 2; ++nt)
                    acc[mt][nt] = __builtin_amdgcn_mfma_f32_16x16x32_bf16(
                        bfr[nt], af[mt], acc[mt][nt], 0, 0, 0);
        }
    }

    // swapped: row = ...+l15, col = ...+quad*4+r -> float4 res/out
#pragma unroll
    for (int nt = 0; nt < 2; ++nt) {
        int colb = n0 + wn * 32 + nt * 16 + quad * 4;
        f32x4 b4 = *(const f32x4*)&bias[colb];
#pragma unroll
        for (int mt = 0; mt < 4; ++mt) {
            int row = m0 + wm * 64 + mt * 16 + l15;
            f32x4 rv = *(const f32x4*)&res[(size_t)row * N + colb];
            f32x4 ov;
#pragma unroll
            for (int r = 0; r < 4; ++r) ov[r] = acc[mt][nt][r] + b4[r] + rv[r];
            *(f32x4*)&outp[(size_t)row * N + colb] = ov;
        }
    }
}

// ---------- bf16 MFMA flash attention, merged q-tile pair -------------------
// Each block processes q-tiles (qta=pair, qtb=31-pair) in ONE merged kt-loop:
// tile A's compute (kt <= qta) rides in the same barrier windows and reads
// the SAME staged K/V as tile B -- staging drops 33 -> qtb+1 tiles per block
// (avg -26%) and windows get denser (better latency hiding). Ps reuse A-then-B
// is safe without barriers: each wave owns rows [wave*16, wave*16+16) of P
// exclusively (write+read wave-local, DS ops in wave order).
// Fixed-max softmax p = exp2(s*0.125*log2e - 4*log2e) via raw v_exp_f32;
// constant cancels in p/l. Row-sum via MFMA with all-ones B fragment.
// P-store swizzle: idx ^= quad<<4 (write) / ((l15>>2)&3)<<4 (read).
template <bool DIAG>
__device__ __forceinline__ void attn_kt(
        const short* __restrict__ Ks, const short* __restrict__ Vs,
        short* __restrict__ Ps, int cb,
        const short8* qf, short8 ones,
        f32x4* o, f32x4& lacc,
        int wave, int quad, int l15, int pswz) {
    f32x4 sacc[4];
#pragma unroll
    for (int nt = 0; nt < 4; ++nt) sacc[nt] = (f32x4){0.f, 0.f, 0.f, 0.f};
#pragma unroll
    for (int nt = 0; nt < 4; ++nt)
#pragma unroll
        for (int ks = 0; ks < 2; ++ks) {
            short8 kf = *(const short8*)&Ks[cb + ks * 2048 + (nt * 16 + l15) * 32 + quad * 8];
            sacc[nt] = __builtin_amdgcn_mfma_f32_16x16x32_bf16(qf[ks], kf, sacc[nt], 0, 0, 0);
        }

#pragma unroll
    for (int nt = 0; nt < 4; ++nt) {
        int scol = nt * 16 + l15;
        int base = (scol >> 5) * 2048 + (scol & 31);
#pragma unroll
        for (int r = 0; r < 4; ++r) {
            // exp(s*0.125 - 4) = exp2(s*0.18033688 - 5.77078): 1 fma + 1 v_exp
            float p = exp2_raw(fmaf(sacc[nt][r], 0.18033688011112042f,
                                    -5.770780163555854f));
            if (DIAG && (scol > wave * 16 + quad * 4 + r)) p = 0.f;
            Ps[(base + (wave * 16 + quad * 4 + r) * 32) ^ (quad << 4)] = f2bf_fast(p);
        }
    }

    short8 pf0 = *(const short8*)&Ps[((wave * 16 + l15) * 32 + quad * 8) ^ pswz];
    short8 pf1 = *(const short8*)&Ps[(2048 + (wave * 16 + l15) * 32 + quad * 8) ^ pswz];
    lacc = __builtin_amdgcn_mfma_f32_16x16x32_bf16(pf0, ones, lacc, 0, 0, 0);
    lacc = __builtin_amdgcn_mfma_f32_16x16x32_bf16(pf1, ones, lacc, 0, 0, 0);
#pragma unroll
    for (int nt = 0; nt < 4; ++nt) {
        short8 vf0 = *(const short8*)&Vs[cb + (nt * 16 + l15) * 32 + quad * 8];
        short8 vf1 = *(const short8*)&Vs[cb + 2048 + (nt * 16 + l15) * 32 + quad * 8];
        o[nt] = __builtin_amdgcn_mfma_f32_16x16x32_bf16(pf0, vf0, o[nt], 0, 0, 0);
        o[nt] = __builtin_amdgcn_mfma_f32_16x16x32_bf16(pf1, vf1, o[nt], 0, 0, 0);
    }
}

__device__ __forceinline__ void attn_pair(
        const short* __restrict__ qkv, const short* __restrict__ Vt,
        short* __restrict__ y, int bh, int qta, int qtb,
        short* Ks, short* Vs, short* Ps) {
    int tid = threadIdx.x;
    int wave = tid >> 6, lane = tid & 63;
    int quad = lane >> 4, l15 = lane & 15;
    int h = bh % N_HEAD, b = bh / N_HEAD;
    size_t bT = (size_t)b * SEQ;
    int sr = lane >> 2, sc = (lane & 3) * 8;

    const short ONE_BF = (short)0x3F80;
    short8 ones;
#pragma unroll
    for (int j = 0; j < 8; ++j) ones[j] = ONE_BF;

    // Q fragments for both tiles, straight from global (L2-resident)
    const short* qrowA = qkv + (bT + qta * 64 + wave * 16 + l15) * 2304 + h * 64 + quad * 8;
    const short* qrowB = qkv + (bT + qtb * 64 + wave * 16 + l15) * 2304 + h * 64 + quad * 8;
    short8 qfA[2], qfB[2];
    qfA[0] = *(const short8*)qrowA; qfA[1] = *(const short8*)(qrowA + 32);
    qfB[0] = *(const short8*)qrowB; qfB[1] = *(const short8*)(qrowB + 32);

    // hoisted staging pointers: computed once, constant-stride advance per kt
    const short* gp[4];
    int lo[4], adv[4];
#pragma unroll
    for (int j = 0; j < 4; ++j) {
        int c = wave * 4 + j;
        if (c < 8) {
            int sub = c >> 2, r0 = (c & 3) * 16;
            gp[j] = qkv + (bT + r0 + sr) * 2304 + 768 + h * 64 + sub * 32 + sc;
            lo[j] = sub * 2048 + r0 * 32;
            adv[j] = 64 * 2304;          // next K-tile: +64 token rows
        } else {
            int cv = c - 8;
            int sub = cv >> 2, r0 = (cv & 3) * 16;
            gp[j] = Vt + ((size_t)bh * 64 + r0 + sr) * SEQ + sub * 32 + sc;
            lo[j] = sub * 2048 + r0 * 32;
            adv[j] = 64;                 // next K-tile: +64 t columns
        }
    }

    // stage K/V tile 0 (buf 0)
#pragma unroll
    for (int j = 0; j < 4; ++j) {
        gld16(gp[j], (wave * 4 + j < 8) ? &Ks[lo[j]] : &Vs[lo[j]]);
        gp[j] += adv[j];
    }
    __syncthreads();

    f32x4 oA[4], oB[4];
#pragma unroll
    for (int nt = 0; nt < 4; ++nt) {
        oA[nt] = (f32x4){0.f, 0.f, 0.f, 0.f};
        oB[nt] = (f32x4){0.f, 0.f, 0.f, 0.f};
    }
    f32x4 laccA = (f32x4){0.f, 0.f, 0.f, 0.f};
    f32x4 laccB = (f32x4){0.f, 0.f, 0.f, 0.f};

    const int pswz = ((l15 >> 2) & 3) << 4;   // read-side P swizzle key

    // merged loop over kt = 0..qtb-1 (prefetch kt+1); diag(B) peeled at qtb.
    // qta < qtb always (qta <= 15 < 16 <= qtb).
    for (int kt = 0; kt < qtb; ++kt) {
        int cb = (kt & 1) * 4096;
        if (kt) __syncthreads();       // buf[kt&1] ready; other buf free
        int nb = ((kt + 1) & 1) * 4096;
#pragma unroll
        for (int j = 0; j < 4; ++j) {
            gld16(gp[j], (wave * 4 + j < 8) ? &Ks[nb + lo[j]] : &Vs[nb + lo[j]]);
            gp[j] += adv[j];
        }
        if (kt < qta)
            attn_kt<false>(Ks, Vs, Ps, cb, qfA, ones, oA, laccA, wave, quad, l15, pswz);
        else if (kt == qta)
            attn_kt<true>(Ks, Vs, Ps, cb, qfA, ones, oA, laccA, wave, quad, l15, pswz);
        attn_kt<false>(Ks, Vs, Ps, cb, qfB, ones, oB, laccB, wave, quad, l15, pswz);
    }

    // diagonal tile of B (kt == qtb)
    __syncthreads();
    attn_kt<true>(Ks, Vs, Ps, (qtb & 1) * 4096, qfB, ones, oB, laccB,
                  wave, quad, l15, pswz);

    // epilogues
    float invA[4], invB[4];
#pragma unroll
    for (int r = 0; r < 4; ++r) { invA[r] = 1.f / laccA[r]; invB[r] = 1.f / laccB[r]; }
#pragma unroll
    for (int nt = 0; nt < 4; ++nt)
#pragma unroll
        for (int r = 0; r < 4; ++r) {
            y[(bT + qta * 64 + wave * 16 + quad * 4 + r) * N_EMBD + h * 64 + nt * 16 + l15] =
                f2bf(oA[nt][r] * invA[r]);
            y[(bT + qtb * 64 + wave * 16 + quad * 4 + r) * N_EMBD + h * 64 + nt * 16 + l15] =
                f2bf(oB[nt][r] * invB[r]);
        }
}

// Balanced pairing + XCD pinning (blockIdx.x = bh; 48%8==0 -> 6 heads/XCD).
// LDS 40 KB -> 4 blocks/CU (16 waves); launch_bounds(256,4) caps regs at 128.
__global__ __launch_bounds__(256, 4) void attn_mfma(
        const short* __restrict__ qkv, const short* __restrict__ Vt,
        short* __restrict__ y) {
    __shared__ short Ks[8192], Vs[8192], Ps[4096];   // 40 KB
    int pair = blockIdx.y;
    attn_pair(qkv, Vt, y, blockIdx.x, pair, NQT - 1 - pair, Ks, Vs, Ps);
}

extern "C" void kernel_launch(void* const* d_in, const int* in_sizes, int n_in,
                              void* d_out, int out_size, void* d_ws, size_t ws_size,
                              hipStream_t stream) {
    const float* x         = (const float*)d_in[0];
    const float* ln1_w     = (const float*)d_in[1];
    const float* ln1_b     = (const float*)d_in[2];
    const float* W_attn    = (const float*)d_in[3];
    const float* b_attn    = (const float*)d_in[4];
    const float* W_attn_pr = (const float*)d_in[5];
    const float* b_attn_pr = (const float*)d_in[6];
    const float* ln2_w     = (const float*)d_in[7];
    const float* ln2_b     = (const float*)d_in[8];
    const float* W_fc      = (const float*)d_in[9];
    const float* b_fc      = (const float*)d_in[10];
    const float* W_mlp_pr  = (const float*)d_in[11];
    const float* b_mlp_pr  = (const float*)d_in[12];
    float* out = (float*)d_out;

    const int M = TOKENS, C = N_EMBD;
    char* ws = (char*)d_ws;
    size_t region0 = (size_t)M * 3072 * 2;                  // qkv (37.7MB) | fc (50.3MB)
    short* qkv_bf = (short*)ws;
    short* fc_bf  = (short*)ws;
    size_t off = region0;
    short* VtB   = (short*)(ws + off); off += (size_t)48 * 64 * SEQ * 2;
    short* yb    = (short*)(ws + off); off += (size_t)M * C * 2;
    short* lnb   = (short*)(ws + off); off += (size_t)M * C * 2;
    float* x1    = (float*)(ws + off); off += (size_t)M * C * 4;
    short* WaT   = (short*)(ws + off); off += (size_t)2304 * 768 * 2;
    short* WpT   = (short*)(ws + off); off += (size_t)768 * 768 * 2;
    short* WfT   = (short*)(ws + off); off += (size_t)3072 * 768 * 2;
    short* WmT   = (short*)(ws + off); off += (size_t)768 * 3072 * 2;

    // 0. all weight transposes, one launch (fp32 [K][N] -> bf16 [N][K])
    wT_all<<<6912, 256, 0, stream>>>(W_attn, WaT, W_attn_pr, WpT,
                                     W_fc, WfT, W_mlp_pr, WmT);

    // 1. ln1 -> bf16 (wave per row)
    ln_bf_kernel<<<M / 4, 256, 0, stream>>>(x, ln1_w, ln1_b, lnb);

    // 2. qkv = ln1 @ W_attn + b -> bf16 [M][2304]; V tiles go straight to VtB
    gemm_mfma<0, 1, 0><<<dim3(M / 128, 2304 / 128), 256, 0, stream>>>(
        lnb, WaT, b_attn, qkv_bf, VtB, M, 2304, 768);

    // 3. attention -> yb bf16 (merged pair, bh-pinned XCDs, dbuf K/V)
    attn_mfma<<<dim3(BATCH * N_HEAD, NQT / 2), 256, 0, stream>>>(qkv_bf, VtB, yb);

    // 4. x1 = x + yb @ W_proj + b   (fp32 out), BK=64 n64
    gemm_mfma_n64<<<dim3(M / 128, 768 / 64), 256, 0, stream>>>(
        yb, WpT, b_attn_pr, x, x1, M, 768, 768);

    // 5. ln2 -> bf16
    ln_bf_kernel<<<M / 4, 256, 0, stream>>>(x1, ln2_w, ln2_b, lnb);

    // 6. fc = gelu(ln2 @ W_fc + b) -> bf16 [M][3072]  (BK=64, swapped)
    gemm_mfma<1, 0, 1><<<dim3(M / 128, 3072 / 128), 256, 0, stream>>>(
        lnb, WfT, b_fc, fc_bf, nullptr, M, 3072, 768);

    // 7. out = x1 + fc @ W_mlp + b  (fp32 out), BK=64 n64
    gemm_mfma_n64<<<dim3(M / 128, 768 / 64), 256, 0, stream>>>(
        fc_bf, WmT, b_mlp_pr, x1, out, M, 768, 3072);
}

// Round 8
// 344.757 us; speedup vs baseline: 1.1302x; 1.0162x over previous
//
#include <hip/hip_runtime.h>
#include <hip/hip_bf16.h>
#include <math.h>

#define N_EMBD 768
#define N_HEAD 12
#define HEAD_DIM 64
#define TOKENS 8192   // B*T
#define SEQ 2048
#define BATCH 4
#define NQT (SEQ / 64)   // 32 query tiles per (b,h)

typedef __attribute__((ext_vector_type(8))) short short8;   // 8 bf16 = 4 VGPRs
typedef __attribute__((ext_vector_type(4))) short short4v;  // 4 bf16 = 8 B
typedef __attribute__((ext_vector_type(4))) float f32x4;

__device__ __forceinline__ short f2bf(float f) {
    unsigned u = __builtin_bit_cast(unsigned, f);
    unsigned r = (u + 0x7fffu + ((u >> 16) & 1u)) >> 16;   // RNE
    return (short)r;
}
__device__ __forceinline__ short f2bf_fast(float f) {      // round-half-up
    unsigned u = __builtin_bit_cast(unsigned, f);
    return (short)((u + 0x8000u) >> 16);
}

// raw v_exp_f32 (exp2): exp2f() without fast-math lowers to a guarded
// multi-instruction sequence; the bare builtin is 1 trans instr.
__device__ __forceinline__ float exp2_raw(float x) {
#if __has_builtin(__builtin_amdgcn_exp2f)
    return __builtin_amdgcn_exp2f(x);
#else
    return exp2f(x);
#endif
}

// fast GELU: x * sigmoid(1.5957691x(1+0.044715x^2)); |err| < ~4e-4
__device__ __forceinline__ float gelu_fast(float x) {
    float z = 1.5957691216057308f * x * (1.0f + 0.044715f * x * x);
    return x / (1.0f + __expf(-z));
}

// async global->LDS, 16B per lane; lds dest = wave-uniform base + lane*16
__device__ __forceinline__ void gld16(const void* g, void* l) {
    __builtin_amdgcn_global_load_lds(
        (const __attribute__((address_space(1))) unsigned int*)g,
        (__attribute__((address_space(3))) unsigned int*)l, 16, 0, 0);
}

// ---------- merged weight transpose: 4 matrices, one launch -----------------
// W[K][N] f32 -> Wt[N][K] bf16, 32x32 tiles, flat tile id over all 4.
__global__ __launch_bounds__(256) void wT_all(
        const float* __restrict__ Wa, short* __restrict__ Ta,    // 768x2304
        const float* __restrict__ Wp, short* __restrict__ Tp,    // 768x768
        const float* __restrict__ Wf, short* __restrict__ Tf,    // 768x3072
        const float* __restrict__ Wm, short* __restrict__ Tm) {  // 3072x768
    __shared__ float T[32][33];
    int id = blockIdx.x;
    const float* W; short* Wt; int K, N;
    if (id < 1728)      { W = Wa; Wt = Ta; K = 768;  N = 2304; }
    else if (id < 2304) { W = Wp; Wt = Tp; K = 768;  N = 768;  id -= 1728; }
    else if (id < 4608) { W = Wf; Wt = Tf; K = 768;  N = 3072; id -= 2304; }
    else                { W = Wm; Wt = Tm; K = 3072; N = 768;  id -= 4608; }
    int tn = N >> 5;
    int n0 = (id % tn) * 32, k0 = (id / tn) * 32;
    int c = threadIdx.x & 31, r0 = threadIdx.x >> 5;
#pragma unroll
    for (int i = 0; i < 32; i += 8)
        T[r0 + i][c] = W[(size_t)(k0 + r0 + i) * N + n0 + c];
    __syncthreads();
#pragma unroll
    for (int i = 0; i < 32; i += 8)
        Wt[(size_t)(n0 + r0 + i) * K + k0 + c] = f2bf(T[c][r0 + i]);
}

// ---------- LayerNorm fp32 in -> bf16 out, one WAVE per row (no barriers) ---
__global__ __launch_bounds__(256) void ln_bf_kernel(const float* __restrict__ x,
                                                    const float* __restrict__ w,
                                                    const float* __restrict__ b,
                                                    short* __restrict__ out) {
    int row = blockIdx.x * 4 + (threadIdx.x >> 6);
    int lane = threadIdx.x & 63;
    const float4* xr = (const float4*)(x + (size_t)row * N_EMBD);
    const float4* wr = (const float4*)w;
    const float4* br = (const float4*)b;

    float4 v[3];
#pragma unroll
    for (int i = 0; i < 3; ++i) v[i] = xr[lane + 64 * i];
    float s = 0.f;
#pragma unroll
    for (int i = 0; i < 3; ++i) s += v[i].x + v[i].y + v[i].z + v[i].w;
#pragma unroll
    for (int off = 1; off < 64; off <<= 1) s += __shfl_xor(s, off, 64);
    float mean = s * (1.f / 768.f);

    float var = 0.f;
#pragma unroll
    for (int i = 0; i < 3; ++i) {
        float a0 = v[i].x - mean, a1 = v[i].y - mean,
              a2 = v[i].z - mean, a3 = v[i].w - mean;
        var += a0 * a0 + a1 * a1 + a2 * a2 + a3 * a3;
    }
#pragma unroll
    for (int off = 1; off < 64; off <<= 1) var += __shfl_xor(var, off, 64);
    float inv = 1.f / (sqrtf(var * (1.f / 768.f)) + 1e-6f);

    short4v* yr = (short4v*)(out + (size_t)row * N_EMBD);
#pragma unroll
    for (int i = 0; i < 3; ++i) {
        float4 wv = wr[lane + 64 * i], bv = br[lane + 64 * i];
        short4v o;
        o[0] = f2bf(wv.x * (v[i].x - mean) * inv + bv.x);
        o[1] = f2bf(wv.y * (v[i].y - mean) * inv + bv.y);
        o[2] = f2bf(wv.z * (v[i].z - mean) * inv + bv.z);
        o[3] = f2bf(wv.w * (v[i].w - mean) * inv + bv.w);
        yr[lane + 64 * i] = o;
    }
}

// ---------- bf16 MFMA GEMM, 128x128 tile, BK=64, single-barrier dbuf --------
// BK=64: half the barrier+drain windows of BK=32 (24->12 at K=768), 32 MFMA
// per wave per window (2-for-2 winning lever this session). LDS 64 KB ->
// 2 blocks/CU.
// SWAP=1: operands swapped (mfma(b,a)): acc reg r walks consecutive N-cols.
//   RES=0: 8B short4v bf16 stores (+optional ACT).
//   RES=1: fp32 out with float4 residual add (projection epilogue).
// SWAP=0 keeps r on M-rows (VOUT V-transpose path of the qkv GEMM).
// VOUT: for V n-tiles (n0>=1536), write transposed into Vt[bh][d][t] as
// packed short4 (4 consecutive t) and skip the normal write.
template <int ACT, int VOUT, int SWAP, int RES>
__global__ __launch_bounds__(256) void gemm_mfma(
        const short* __restrict__ A,     // [M][K] bf16
        const short* __restrict__ Bt,    // [N][K] bf16
        const float* __restrict__ bias,
        const float* __restrict__ res,   // [M][N] fp32 (RES only)
        void* __restrict__ outp,         // bf16 (RES=0) / fp32 (RES=1)
        short* __restrict__ vt,          // [48][64][SEQ] (VOUT only)
        int M, int N, int K) {
    __shared__ short As[16384];  // 2 buf x (2 ks x 128 rows x 32 k)
    __shared__ short Bs[16384];
    int tid = threadIdx.x;
    int wave = tid >> 6, lane = tid & 63;
    int quad = lane >> 4, l15 = lane & 15;
    int m0 = blockIdx.x * 128, n0 = blockIdx.y * 128;
    int wm = wave >> 1, wn = wave & 1;
    int sr = lane >> 2, sc = (lane & 3) * 8;

    f32x4 acc[4][4];
#pragma unroll
    for (int i = 0; i < 4; ++i)
#pragma unroll
        for (int j = 0; j < 4; ++j) acc[i][j] = (f32x4){0.f, 0.f, 0.f, 0.f};

    // 32 chunks/tile (16 A + 16 B), 8 per wave; chunk = 16 rows x 32 k (1 KB)
    const short* gp[8];
    int lo[8];
    bool ia[8];
#pragma unroll
    for (int j = 0; j < 8; ++j) {
        int c = wave * 8 + j;
        if (c < 16) {
            int ks = c >> 3, r0 = (c & 7) * 16;
            gp[j] = A + (size_t)(m0 + r0 + sr) * K + ks * 32 + sc;
            lo[j] = ks * 4096 + r0 * 32; ia[j] = true;
        } else {
            int cc = c - 16, ks = cc >> 3, r0 = (cc & 7) * 16;
            gp[j] = Bt + (size_t)(n0 + r0 + sr) * K + ks * 32 + sc;
            lo[j] = ks * 4096 + r0 * 32; ia[j] = false;
        }
    }
    int nk = K >> 6;

    auto stage = [&](int t) {
        int bb = (t & 1) * 8192;
        int kn = t << 6;
#pragma unroll
        for (int j = 0; j < 8; ++j)
            gld16(gp[j] + kn, ia[j] ? &As[bb + lo[j]] : &Bs[bb + lo[j]]);
    };

    stage(0);

    for (int it = 0; it < nk; ++it) {
        int cb = (it & 1) * 8192;
        __syncthreads();               // buf[it&1] ready; other buf free
        if (it + 1 < nk) stage(it + 1);
#pragma unroll
        for (int ks = 0; ks < 2; ++ks) {
            short8 af[4], bfr[4];
#pragma unroll
            for (int mt = 0; mt < 4; ++mt)
                af[mt] = *(const short8*)&As[cb + ks * 4096 +
                                             (wm * 64 + mt * 16 + l15) * 32 + quad * 8];
#pragma unroll
            for (int nt = 0; nt < 4; ++nt)
                bfr[nt] = *(const short8*)&Bs[cb + ks * 4096 +
                                              (wn * 64 + nt * 16 + l15) * 32 + quad * 8];
#pragma unroll
            for (int mt = 0; mt < 4; ++mt)
#pragma unroll
                for (int nt = 0; nt < 4; ++nt) {
                    if (SWAP)
                        acc[mt][nt] = __builtin_amdgcn_mfma_f32_16x16x32_bf16(
                            bfr[nt], af[mt], acc[mt][nt], 0, 0, 0);
                    else
                        acc[mt][nt] = __builtin_amdgcn_mfma_f32_16x16x32_bf16(
                            af[mt], bfr[nt], acc[mt][nt], 0, 0, 0);
                }
        }
    }

    if (SWAP) {
        // r walks N-cols: row = ...+l15 (per-lane), col = ...+quad*4+r
#pragma unroll
        for (int nt = 0; nt < 4; ++nt) {
            int colb = n0 + wn * 64 + nt * 16 + quad * 4;
            f32x4 b4 = *(const f32x4*)&bias[colb];
#pragma unroll
            for (int mt = 0; mt < 4; ++mt) {
                int row = m0 + wm * 64 + mt * 16 + l15;
                if (RES) {
                    f32x4 rv = *(const f32x4*)&res[(size_t)row * N + colb];
                    f32x4 ov;
#pragma unroll
                    for (int r = 0; r < 4; ++r)
                        ov[r] = acc[mt][nt][r] + b4[r] + rv[r];
                    *(f32x4*)&((float*)outp)[(size_t)row * N + colb] = ov;
                } else {
                    short4v o4;
#pragma unroll
                    for (int r = 0; r < 4; ++r) {
                        float v = acc[mt][nt][r] + b4[r];
                        if (ACT) v = gelu_fast(v);
                        o4[r] = f2bf(v);
                    }
                    *(short4v*)&((short*)outp)[(size_t)row * N + colb] = o4;
                }
            }
        }
        return;
    }

    if (VOUT && n0 >= 1536) {
        // V tile: write transposed Vt[bh*64+d][t], 4 consecutive t per store
#pragma unroll
        for (int mt = 0; mt < 4; ++mt) {
            int row0 = m0 + wm * 64 + mt * 16 + quad * 4;
            int b = row0 >> 11, t0 = row0 & 2047;
#pragma unroll
            for (int nt = 0; nt < 4; ++nt) {
                int col = n0 + wn * 64 + nt * 16 + l15;
                int vcol = col - 1536;
                int bh = b * N_HEAD + (vcol >> 6);
                int d = vcol & 63;
                float bi = bias[col];
                short4v o;
#pragma unroll
                for (int r = 0; r < 4; ++r) o[r] = f2bf(acc[mt][nt][r] + bi);
                *(short4v*)&vt[((size_t)bh * 64 + d) * SEQ + t0] = o;
            }
        }
        return;
    }

#pragma unroll
    for (int mt = 0; mt < 4; ++mt) {
        int row0 = m0 + wm * 64 + mt * 16 + quad * 4;
#pragma unroll
        for (int nt = 0; nt < 4; ++nt) {
            int col = n0 + wn * 64 + nt * 16 + l15;
            float bi = bias[col];
#pragma unroll
            for (int r = 0; r < 4; ++r) {
                float v = acc[mt][nt][r] + bi;
                if (ACT) v = gelu_fast(v);
                ((short*)outp)[(size_t)(row0 + r) * N + col] = f2bf(v);
            }
        }
    }
}

// ---------- bf16 MFMA flash attention, merged q-tile pair -------------------
// Each block processes q-tiles (qta=pair, qtb=31-pair) in ONE merged kt-loop:
// tile A's compute (kt <= qta) rides in the same barrier windows and reads
// the SAME staged K/V as tile B -- staging drops 33 -> qtb+1 tiles per block
// (avg -26%) and windows get denser (better latency hiding). Ps reuse A-then-B
// is safe without barriers: each wave owns rows [wave*16, wave*16+16) of P
// exclusively (write+read wave-local, DS ops in wave order).
// Fixed-max softmax p = exp2(s*0.125*log2e - 4*log2e) via raw v_exp_f32;
// constant cancels in p/l. Row-sum via MFMA with all-ones B fragment.
// P-store swizzle: idx ^= quad<<4 (write) / ((l15>>2)&3)<<4 (read).
template <bool DIAG>
__device__ __forceinline__ void attn_kt(
        const short* __restrict__ Ks, const short* __restrict__ Vs,
        short* __restrict__ Ps, int cb,
        const short8* qf, short8 ones,
        f32x4* o, f32x4& lacc,
        int wave, int quad, int l15, int pswz) {
    f32x4 sacc[4];
#pragma unroll
    for (int nt = 0; nt < 4; ++nt) sacc[nt] = (f32x4){0.f, 0.f, 0.f, 0.f};
#pragma unroll
    for (int nt = 0; nt < 4; ++nt)
#pragma unroll
        for (int ks = 0; ks < 2; ++ks) {
            short8 kf = *(const short8*)&Ks[cb + ks * 2048 + (nt * 16 + l15) * 32 + quad * 8];
            sacc[nt] = __builtin_amdgcn_mfma_f32_16x16x32_bf16(qf[ks], kf, sacc[nt], 0, 0, 0);
        }

#pragma unroll
    for (int nt = 0; nt < 4; ++nt) {
        int scol = nt * 16 + l15;
        int base = (scol >> 5) * 2048 + (scol & 31);
#pragma unroll
        for (int r = 0; r < 4; ++r) {
            // exp(s*0.125 - 4) = exp2(s*0.18033688 - 5.77078): 1 fma + 1 v_exp
            float p = exp2_raw(fmaf(sacc[nt][r], 0.18033688011112042f,
                                    -5.770780163555854f));
            if (DIAG && (scol > wave * 16 + quad * 4 + r)) p = 0.f;
            Ps[(base + (wave * 16 + quad * 4 + r) * 32) ^ (quad << 4)] = f2bf_fast(p);
        }
    }

    short8 pf0 = *(const short8*)&Ps[((wave * 16 + l15) * 32 + quad * 8) ^ pswz];
    short8 pf1 = *(const short8*)&Ps[(2048 + (wave * 16 + l15) * 32 + quad * 8) ^ pswz];
    lacc = __builtin_amdgcn_mfma_f32_16x16x32_bf16(pf0, ones, lacc, 0, 0, 0);
    lacc = __builtin_amdgcn_mfma_f32_16x16x32_bf16(pf1, ones, lacc, 0, 0, 0);
#pragma unroll
    for (int nt = 0; nt < 4; ++nt) {
        short8 vf0 = *(const short8*)&Vs[cb + (nt * 16 + l15) * 32 + quad * 8];
        short8 vf1 = *(const short8*)&Vs[cb + 2048 + (nt * 16 + l15) * 32 + quad * 8];
        o[nt] = __builtin_amdgcn_mfma_f32_16x16x32_bf16(pf0, vf0, o[nt], 0, 0, 0);
        o[nt] = __builtin_amdgcn_mfma_f32_16x16x32_bf16(pf1, vf1, o[nt], 0, 0, 0);
    }
}

__device__ __forceinline__ void attn_pair(
        const short* __restrict__ qkv, const short* __restrict__ Vt,
        short* __restrict__ y, int bh, int qta, int qtb,
        short* Ks, short* Vs, short* Ps) {
    int tid = threadIdx.x;
    int wave = tid >> 6, lane = tid & 63;
    int quad = lane >> 4, l15 = lane & 15;
    int h = bh % N_HEAD, b = bh / N_HEAD;
    size_t bT = (size_t)b * SEQ;
    int sr = lane >> 2, sc = (lane & 3) * 8;

    const short ONE_BF = (short)0x3F80;
    short8 ones;
#pragma unroll
    for (int j = 0; j < 8; ++j) ones[j] = ONE_BF;

    // Q fragments for both tiles, straight from global (L2-resident)
    const short* qrowA = qkv + (bT + qta * 64 + wave * 16 + l15) * 2304 + h * 64 + quad * 8;
    const short* qrowB = qkv + (bT + qtb * 64 + wave * 16 + l15) * 2304 + h * 64 + quad * 8;
    short8 qfA[2], qfB[2];
    qfA[0] = *(const short8*)qrowA; qfA[1] = *(const short8*)(qrowA + 32);
    qfB[0] = *(const short8*)qrowB; qfB[1] = *(const short8*)(qrowB + 32);

    // hoisted staging pointers: computed once, constant-stride advance per kt
    const short* gp[4];
    int lo[4], adv[4];
#pragma unroll
    for (int j = 0; j < 4; ++j) {
        int c = wave * 4 + j;
        if (c < 8) {
            int sub = c >> 2, r0 = (c & 3) * 16;
            gp[j] = qkv + (bT + r0 + sr) * 2304 + 768 + h * 64 + sub * 32 + sc;
            lo[j] = sub * 2048 + r0 * 32;
            adv[j] = 64 * 2304;          // next K-tile: +64 token rows
        } else {
            int cv = c - 8;
            int sub = cv >> 2, r0 = (cv & 3) * 16;
            gp[j] = Vt + ((size_t)bh * 64 + r0 + sr) * SEQ + sub * 32 + sc;
            lo[j] = sub * 2048 + r0 * 32;
            adv[j] = 64;                 // next K-tile: +64 t columns
        }
    }

    // stage K/V tile 0 (buf 0)
#pragma unroll
    for (int j = 0; j < 4; ++j) {
        gld16(gp[j], (wave * 4 + j < 8) ? &Ks[lo[j]] : &Vs[lo[j]]);
        gp[j] += adv[j];
    }
    __syncthreads();

    f32x4 oA[4], oB[4];
#pragma unroll
    for (int nt = 0; nt < 4; ++nt) {
        oA[nt] = (f32x4){0.f, 0.f, 0.f, 0.f};
        oB[nt] = (f32x4){0.f, 0.f, 0.f, 0.f};
    }
    f32x4 laccA = (f32x4){0.f, 0.f, 0.f, 0.f};
    f32x4 laccB = (f32x4){0.f, 0.f, 0.f, 0.f};

    const int pswz = ((l15 >> 2) & 3) << 4;   // read-side P swizzle key

    // merged loop over kt = 0..qtb-1 (prefetch kt+1); diag(B) peeled at qtb.
    // qta < qtb always (qta <= 15 < 16 <= qtb).
    for (int kt = 0; kt < qtb; ++kt) {
        int cb = (kt & 1) * 4096;
        if (kt) __syncthreads();       // buf[kt&1] ready; other buf free
        int nb = ((kt + 1) & 1) * 4096;
#pragma unroll
        for (int j = 0; j < 4; ++j) {
            gld16(gp[j], (wave * 4 + j < 8) ? &Ks[nb + lo[j]] : &Vs[nb + lo[j]]);
            gp[j] += adv[j];
        }
        if (kt < qta)
            attn_kt<false>(Ks, Vs, Ps, cb, qfA, ones, oA, laccA, wave, quad, l15, pswz);
        else if (kt == qta)
            attn_kt<true>(Ks, Vs, Ps, cb, qfA, ones, oA, laccA, wave, quad, l15, pswz);
        attn_kt<false>(Ks, Vs, Ps, cb, qfB, ones, oB, laccB, wave, quad, l15, pswz);
    }

    // diagonal tile of B (kt == qtb)
    __syncthreads();
    attn_kt<true>(Ks, Vs, Ps, (qtb & 1) * 4096, qfB, ones, oB, laccB,
                  wave, quad, l15, pswz);

    // epilogues
    float invA[4], invB[4];
#pragma unroll
    for (int r = 0; r < 4; ++r) { invA[r] = 1.f / laccA[r]; invB[r] = 1.f / laccB[r]; }
#pragma unroll
    for (int nt = 0; nt < 4; ++nt)
#pragma unroll
        for (int r = 0; r < 4; ++r) {
            y[(bT + qta * 64 + wave * 16 + quad * 4 + r) * N_EMBD + h * 64 + nt * 16 + l15] =
                f2bf(oA[nt][r] * invA[r]);
            y[(bT + qtb * 64 + wave * 16 + quad * 4 + r) * N_EMBD + h * 64 + nt * 16 + l15] =
                f2bf(oB[nt][r] * invB[r]);
        }
}

// Balanced pairing + XCD pinning (blockIdx.x = bh; 48%8==0 -> 6 heads/XCD).
// LDS 40 KB -> 4 blocks/CU (16 waves); launch_bounds(256,4) caps regs at 128.
__global__ __launch_bounds__(256, 4) void attn_mfma(
        const short* __restrict__ qkv, const short* __restrict__ Vt,
        short* __restrict__ y) {
    __shared__ short Ks[8192], Vs[8192], Ps[4096];   // 40 KB
    int pair = blockIdx.y;
    attn_pair(qkv, Vt, y, blockIdx.x, pair, NQT - 1 - pair, Ks, Vs, Ps);
}

extern "C" void kernel_launch(void* const* d_in, const int* in_sizes, int n_in,
                              void* d_out, int out_size, void* d_ws, size_t ws_size,
                              hipStream_t stream) {
    const float* x         = (const float*)d_in[0];
    const float* ln1_w     = (const float*)d_in[1];
    const float* ln1_b     = (const float*)d_in[2];
    const float* W_attn    = (const float*)d_in[3];
    const float* b_attn    = (const float*)d_in[4];
    const float* W_attn_pr = (const float*)d_in[5];
    const float* b_attn_pr = (const float*)d_in[6];
    const float* ln2_w     = (const float*)d_in[7];
    const float* ln2_b     = (const float*)d_in[8];
    const float* W_fc      = (const float*)d_in[9];
    const float* b_fc      = (const float*)d_in[10];
    const float* W_mlp_pr  = (const float*)d_in[11];
    const float* b_mlp_pr  = (const float*)d_in[12];
    float* out = (float*)d_out;

    const int M = TOKENS, C = N_EMBD;
    char* ws = (char*)d_ws;
    size_t region0 = (size_t)M * 3072 * 2;                  // qkv (37.7MB) | fc (50.3MB)
    short* qkv_bf = (short*)ws;
    short* fc_bf  = (short*)ws;
    size_t off = region0;
    short* VtB   = (short*)(ws + off); off += (size_t)48 * 64 * SEQ * 2;
    short* yb    = (short*)(ws + off); off += (size_t)M * C * 2;
    short* lnb   = (short*)(ws + off); off += (size_t)M * C * 2;
    float* x1    = (float*)(ws + off); off += (size_t)M * C * 4;
    short* WaT   = (short*)(ws + off); off += (size_t)2304 * 768 * 2;
    short* WpT   = (short*)(ws + off); off += (size_t)768 * 768 * 2;
    short* WfT   = (short*)(ws + off); off += (size_t)3072 * 768 * 2;
    short* WmT   = (short*)(ws + off); off += (size_t)768 * 3072 * 2;

    // 0. all weight transposes, one launch (fp32 [K][N] -> bf16 [N][K])
    wT_all<<<6912, 256, 0, stream>>>(W_attn, WaT, W_attn_pr, WpT,
                                     W_fc, WfT, W_mlp_pr, WmT);

    // 1. ln1 -> bf16 (wave per row)
    ln_bf_kernel<<<M / 4, 256, 0, stream>>>(x, ln1_w, ln1_b, lnb);

    // 2. qkv = ln1 @ W_attn + b -> bf16 [M][2304]; V tiles go straight to VtB
    gemm_mfma<0, 1, 0, 0><<<dim3(M / 128, 2304 / 128), 256, 0, stream>>>(
        lnb, WaT, b_attn, nullptr, qkv_bf, VtB, M, 2304, 768);

    // 3. attention -> yb bf16 (merged pair, bh-pinned XCDs, dbuf K/V)
    attn_mfma<<<dim3(BATCH * N_HEAD, NQT / 2), 256, 0, stream>>>(qkv_bf, VtB, yb);

    // 4. x1 = x + yb @ W_proj + b   (fp32 out), 128x128 BK=64, RES epilogue
    gemm_mfma<0, 0, 1, 1><<<dim3(M / 128, 768 / 128), 256, 0, stream>>>(
        yb, WpT, b_attn_pr, x, x1, nullptr, M, 768, 768);

    // 5. ln2 -> bf16
    ln_bf_kernel<<<M / 4, 256, 0, stream>>>(x1, ln2_w, ln2_b, lnb);

    // 6. fc = gelu(ln2 @ W_fc + b) -> bf16 [M][3072]  (BK=64, swapped)
    gemm_mfma<1, 0, 1, 0><<<dim3(M / 128, 3072 / 128), 256, 0, stream>>>(
        lnb, WfT, b_fc, nullptr, fc_bf, nullptr, M, 3072, 768);

    // 7. out = x1 + fc @ W_mlp + b  (fp32 out), 128x128 BK=64, RES epilogue
    gemm_mfma<0, 0, 1, 1><<<dim3(M / 128, 768 / 128), 256, 0, stream>>>(
        fc_bf, WmT, b_mlp_pr, x1, out, nullptr, M, 768, 3072);
}